// Round 19
// baseline (213.432 us; speedup 1.0000x reference)
//
#include <hip/hip_runtime.h>
#include <hip/hip_bf16.h>
#include <math.h>

#define B_   2
#define S_   2048
#define D_   1024
#define H_   16
#define DK_  64
#define F_   4096
#define NTOK (B_ * S_)

typedef __bf16 bf16x8 __attribute__((ext_vector_type(8)));
typedef float  f32x4  __attribute__((ext_vector_type(4)));

__device__ __forceinline__ unsigned short bf16r(float f) {
  unsigned u = __builtin_bit_cast(unsigned, f);
  u += 0x7fffu + ((u >> 16) & 1u);
  return (unsigned short)(u >> 16);
}

__device__ __forceinline__ void gload_lds16(const void* g, void* l) {
  __builtin_amdgcn_global_load_lds(
      (__attribute__((address_space(1))) void*)g,
      (__attribute__((address_space(3))) void*)l, 16, 0, 0);
}

__device__ __forceinline__ unsigned lds_off(void* p) {
  return (unsigned)(size_t)(__attribute__((address_space(3))) void*)p;
}
__device__ __forceinline__ bf16x8 ds_read16(unsigned a) {
  bf16x8 r;
  asm volatile("ds_read_b128 %0, %1" : "=v"(r) : "v"(a));
  return r;
}
__device__ __forceinline__ void ds_write32(unsigned a, unsigned v) {
  asm volatile("ds_write_b32 %0, %1" : : "v"(a), "v"(v));
}
__device__ __forceinline__ void ds_write16b(unsigned a, unsigned v) {
  asm volatile("ds_write_b16 %0, %1" : : "v"(a), "v"(v));
}
__device__ __forceinline__ float fexp2(float x) {
  float r;
  asm volatile("v_exp_f32 %0, %1\n\ts_nop 0" : "=v"(r) : "v"(x));
  return r;
}
__device__ __forceinline__ unsigned cvt_pk_bf16(float lo, float hi) {
  unsigned r;
  asm volatile("v_cvt_pk_bf16_f32 %0, %1, %2" : "=v"(r) : "v"(lo), "v"(hi));
  return r;
}

__device__ __forceinline__ float gelu_fast(float x) {
  float y = 0.7978845608f * x * (1.0f + 0.044715f * x * x);
  float e = fexp2(2.885390082f * y);
  float t = 1.0f - 2.0f / (e + 1.0f);
  return 0.5f * x * (1.0f + t);
}

#define QSCL 0.18033688f  /* (1/8) * log2(e), folded into Q at QKV epilogue */

// ---------------- all weights fp32 -> bf16, one launch ----------------
struct CvtArgs {
  const float* src[6];
  unsigned short* dst[6];
  int start[7];
};
__global__ __launch_bounds__(256) void cvt_all_kernel(CvtArgs a) {
  int i = blockIdx.x * blockDim.x + threadIdx.x;
  if (i >= a.start[6]) return;
  int k = 0;
#pragma unroll
  for (int j = 1; j < 6; ++j)
    if (i >= a.start[j]) k = j;
  int off = i - a.start[k];
  float4 v = reinterpret_cast<const float4*>(a.src[k])[off];
  ushort4 o;
  o.x = bf16r(v.x); o.y = bf16r(v.y); o.z = bf16r(v.z); o.w = bf16r(v.w);
  reinterpret_cast<ushort4*>(a.dst[k])[off] = o;
}

// ---------------- RMSNorm (fp32 in, bf16 out) ----------------
__global__ __launch_bounds__(256) void rmsnorm_kernel(
    const float* __restrict__ x, const float* __restrict__ g,
    unsigned short* __restrict__ out) {
  int row = blockIdx.x;
  int t = threadIdx.x, lane = t & 63, w = t >> 6;
  float4 v = reinterpret_cast<const float4*>(x + (size_t)row * D_)[t];
  float ss = v.x * v.x + v.y * v.y + v.z * v.z + v.w * v.w;
#pragma unroll
  for (int d = 1; d < 64; d <<= 1) ss += __shfl_xor(ss, d);
  __shared__ float red[4];
  if (lane == 0) red[w] = ss;
  __syncthreads();
  float tot = red[0] + red[1] + red[2] + red[3];
  float rstd = rsqrtf(tot * (1.0f / D_) + 1e-5f);
  float4 gv = reinterpret_cast<const float4*>(g)[t];
  ushort4 o;
  o.x = bf16r(v.x * rstd * gv.x);
  o.y = bf16r(v.y * rstd * gv.y);
  o.z = bf16r(v.z * rstd * gv.z);
  o.w = bf16r(v.w * rstd * gv.w);
  reinterpret_cast<ushort4*>(out + (size_t)row * D_)[t] = o;
}

// wave-tile (64x64) LDS-staged coalesced bf16 store (proven round 15)
__device__ __forceinline__ void store_tile_coalesced(
    const f32x4 (&acc)[4][4], unsigned ew, int lane, int lg, int ln,
    unsigned short* __restrict__ dst, size_t stride, int rowbase, int colbase,
    bool gelu, float scl) {
#pragma unroll
  for (int m = 0; m < 4; ++m)
#pragma unroll
    for (int n = 0; n < 4; ++n)
#pragma unroll
      for (int j = 0; j < 4; ++j) {
        int lrow = lg * 4 + m * 16 + j;
        int lcol = n * 16 + ln;
        int g = (lcol >> 3) ^ (lrow & 7);
        float v = acc[m][n][j];
        if (gelu) v = gelu_fast(v);
        ds_write16b(ew + (unsigned)((lrow * 64 + g * 8 + (lcol & 7)) * 2),
                    (unsigned)bf16r(v * scl));
      }
  asm volatile("s_waitcnt lgkmcnt(0)");
  __builtin_amdgcn_sched_barrier(0);
  bf16x8 cv[8];
#pragma unroll
  for (int i = 0; i < 8; ++i) {
    int lrow = i * 8 + (lane >> 3);
    int g = (lane & 7) ^ (lrow & 7);
    cv[i] = ds_read16(ew + (unsigned)((lrow * 64 + g * 8) * 2));
  }
  asm volatile("s_waitcnt lgkmcnt(0)");
  __builtin_amdgcn_sched_barrier(0);
#pragma unroll
  for (int i = 0; i < 8; ++i) {
    int lrow = i * 8 + (lane >> 3);
    *reinterpret_cast<bf16x8*>(
        &dst[(size_t)(rowbase + lrow) * stride + colbase + (lane & 7) * 8]) = cv[i];
  }
}

// ======== ffn1: 256x256 / BK=64 / 8-wave / 2-buf 8-phase schedule (m201) ====
__global__ __launch_bounds__(512, 2) void ffn1_gemm(
    const unsigned short* __restrict__ A, const unsigned short* __restrict__ Bw,
    int M, int N, int K, unsigned short* __restrict__ outB) {
  __shared__ __attribute__((aligned(16))) unsigned short lds[65536];  // 128 KB
  const int t = threadIdx.x, lane = t & 63, w = t >> 6;
  const int wm = w >> 2, wn = w & 3;
  const int lg = lane >> 4, ln = lane & 15;

  const int gx = gridDim.x;  // 16
  int bid = blockIdx.y * gx + blockIdx.x;
  int xcd = bid & 7, c = bid >> 3;
  int RX = gx >> 2, RY = gridDim.y >> 1;
  int bx = (xcd & 3) * RX + (c % RX);
  int by = (xcd >> 2) * RY + (c / RX);
  const int m0 = by * 256, n0 = bx * 256;

  const int nt = K >> 6;      // 16 K-tiles of 64
  const int niter = nt >> 1;  // 8

  auto SA = [&](int tile, int h) {
    unsigned short* dst = &lds[(tile & 1) * 32768 + h * 8192];
    const int k0 = tile << 6;
    const int rb = m0 + h * 128;
#pragma unroll
    for (int i = 0; i < 2; ++i) {
      int g = i * 512 + t;
      int row = g >> 3, sg = (g & 7) ^ (row & 7);
      gload_lds16(A + (size_t)(rb + row) * K + k0 + sg * 8, &dst[g * 8]);
    }
  };
  auto SB = [&](int tile, int h) {
    unsigned short* dst = &lds[(tile & 1) * 32768 + 16384 + h * 8192];
    const int k0 = tile << 6;
    const int rb = n0 + h * 128;
#pragma unroll
    for (int i = 0; i < 2; ++i) {
      int g = i * 512 + t;
      int row = g >> 3, sg = (g & 7) ^ (row & 7);
      gload_lds16(Bw + (size_t)(rb + row) * K + k0 + sg * 8, &dst[g * 8]);
    }
  };

  SA(0, 0); SA(0, 1); SB(0, 0); SB(0, 1); SB(1, 0); SB(1, 1);

  const unsigned base0 = lds_off(lds);
  unsigned offA[8], offB[4];
#pragma unroll
  for (int m = 0; m < 8; ++m) {
    int r = wm * 128 + m * 16 + ln;
    offA[m] = (unsigned)(r * 128 + (lg ^ (r & 7)) * 16);
  }
#pragma unroll
  for (int n = 0; n < 4; ++n) {
    int r = wn * 64 + n * 16 + ln;
    offB[n] = (unsigned)(32768 + r * 128 + (lg ^ (r & 7)) * 16);
  }

  f32x4 acc[8][4] = {};

  asm volatile("s_waitcnt vmcnt(0)");
  __builtin_amdgcn_sched_barrier(0);
  __builtin_amdgcn_s_barrier();

  for (int it = 0; it < niter; ++it) {
    const int t0 = 2 * it, t1 = 2 * it + 1;
    const bool more = (it + 1 < niter);
    const unsigned bb0 = base0 + (unsigned)((t0 & 1) * 65536);
    const unsigned bb1 = base0 + (unsigned)((t1 & 1) * 65536);
    bf16x8 bfr[4][2];
#pragma unroll
    for (int q = 0; q < 4; ++q) {
      bf16x8 af[2][2];
      if (q == 0) {
#pragma unroll
        for (int n = 0; n < 4; ++n) {
          bfr[n][0] = ds_read16(bb0 + offB[n]);
          bfr[n][1] = ds_read16(bb0 + (offB[n] ^ 0x40u));
        }
      }
#pragma unroll
      for (int mm = 0; mm < 2; ++mm) {
        af[mm][0] = ds_read16(bb0 + offA[2 * q + mm]);
        af[mm][1] = ds_read16(bb0 + (offA[2 * q + mm] ^ 0x40u));
      }
      if (q == 0)       SA(t1, 0);
      else if (q == 1)  SA(t1, 1);
      else if (q == 2)  { if (more) SB(t0 + 2, 0); }
      else              { if (more) SB(t0 + 2, 1); }
      if (q == 3) {
        if (more) { asm volatile("s_waitcnt vmcnt(4)"); }
        else      { asm volatile("s_waitcnt vmcnt(0)"); }
        __builtin_amdgcn_sched_barrier(0);
      }
      __builtin_amdgcn_s_barrier();
      asm volatile("s_waitcnt lgkmcnt(0)");
      __builtin_amdgcn_sched_barrier(0);
      __builtin_amdgcn_s_setprio(1);
#pragma unroll
      for (int mm = 0; mm < 2; ++mm)
#pragma unroll
        for (int n = 0; n < 4; ++n) {
          acc[2 * q + mm][n] = __builtin_amdgcn_mfma_f32_16x16x32_bf16(
              af[mm][0], bfr[n][0], acc[2 * q + mm][n], 0, 0, 0);
          acc[2 * q + mm][n] = __builtin_amdgcn_mfma_f32_16x16x32_bf16(
              af[mm][1], bfr[n][1], acc[2 * q + mm][n], 0, 0, 0);
        }
      __builtin_amdgcn_s_setprio(0);
      __builtin_amdgcn_s_barrier();
    }
#pragma unroll
    for (int q = 0; q < 4; ++q) {
      bf16x8 af[2][2];
      if (q == 0) {
#pragma unroll
        for (int n = 0; n < 4; ++n) {
          bfr[n][0] = ds_read16(bb1 + offB[n]);
          bfr[n][1] = ds_read16(bb1 + (offB[n] ^ 0x40u));
        }
      }
#pragma unroll
      for (int mm = 0; mm < 2; ++mm) {
        af[mm][0] = ds_read16(bb1 + offA[2 * q + mm]);
        af[mm][1] = ds_read16(bb1 + (offA[2 * q + mm] ^ 0x40u));
      }
      if (more) {
        if (q == 0)      SA(t0 + 2, 0);
        else if (q == 1) SA(t0 + 2, 1);
        else if (q == 2) SB(t1 + 2, 0);
        else             SB(t1 + 2, 1);
      }
      if (q == 3) {
        if (more) { asm volatile("s_waitcnt vmcnt(4)"); }
        else      { asm volatile("s_waitcnt vmcnt(0)"); }
        __builtin_amdgcn_sched_barrier(0);
      }
      __builtin_amdgcn_s_barrier();
      asm volatile("s_waitcnt lgkmcnt(0)");
      __builtin_amdgcn_sched_barrier(0);
      __builtin_amdgcn_s_setprio(1);
#pragma unroll
      for (int mm = 0; mm < 2; ++mm)
#pragma unroll
        for (int n = 0; n < 4; ++n) {
          acc[2 * q + mm][n] = __builtin_amdgcn_mfma_f32_16x16x32_bf16(
              af[mm][0], bfr[n][0], acc[2 * q + mm][n], 0, 0, 0);
          acc[2 * q + mm][n] = __builtin_amdgcn_mfma_f32_16x16x32_bf16(
              af[mm][1], bfr[n][1], acc[2 * q + mm][n], 0, 0, 0);
        }
      __builtin_amdgcn_s_setprio(0);
      __builtin_amdgcn_s_barrier();
    }
  }

  const unsigned ew = base0 + (unsigned)(w * 8192);
  store_tile_coalesced(*reinterpret_cast<const f32x4(*)[4][4]>(&acc[0]),
                       ew, lane, lg, ln, outB, (size_t)N,
                       m0 + wm * 128, n0 + wn * 64, true, 1.0f);
  store_tile_coalesced(*reinterpret_cast<const f32x4(*)[4][4]>(&acc[4]),
                       ew, lane, lg, ln, outB, (size_t)N,
                       m0 + wm * 128 + 64, n0 + wn * 64, true, 1.0f);
}

// ======== 128x128 / 256-thr / NBUF=4 PAIRED GEMM (qkv, round-16 winner) =====
__global__ __launch_bounds__(256, 2) void qkv_gemm(
    const unsigned short* __restrict__ A, const unsigned short* __restrict__ Bw,
    int M, int N, int K,
    unsigned short* __restrict__ outB, unsigned short* __restrict__ outB2,
    unsigned short* __restrict__ outB3) {
  constexpr int BUFU = 8192;
  __shared__ __attribute__((aligned(16))) unsigned short lds[4 * BUFU];  // 64 KB
  const int t = threadIdx.x, lane = t & 63, w = t >> 6;
  const int wm = w >> 1, wn = w & 1;
  const int lg = lane >> 4, ln = lane & 15;

  const int gx = gridDim.x;
  int bid = blockIdx.y * gx + blockIdx.x;
  int xcd = bid & 7, c = bid >> 3;
  int RX = gx >> 2, RY = gridDim.y >> 1;
  int bx = (xcd & 3) * RX + (c % RX);
  int by = (xcd >> 2) * RY + (c / RX);
  const int m0 = by * 128, n0 = bx * 128;

  const int nt = K >> 5;  // even

  auto stage = [&](int tile) {
    int buf = tile & 3;
    const int k0 = tile << 5;
    unsigned short* la = &lds[buf * BUFU];
    unsigned short* lb = la + 4096;
#pragma unroll
    for (int i = 0; i < 2; ++i) {
      int g = i * 256 + t;
      int Ln = g >> 3, p = g & 7, u = p ^ (Ln & 7);
      int row = 2 * Ln + (u >> 2), cg = u & 3;
      gload_lds16(A + (size_t)(m0 + row) * K + k0 + cg * 8, &la[g * 8]);
    }
#pragma unroll
    for (int i = 0; i < 2; ++i) {
      int g = i * 256 + t;
      int Ln = g >> 3, p = g & 7, u = p ^ (Ln & 7);
      int row = 2 * Ln + (u >> 2), cg = u & 3;
      gload_lds16(Bw + (size_t)(n0 + row) * K + k0 + cg * 8, &lb[g * 8]);
    }
  };

  stage(0);
  stage(1);

  const unsigned base0 = lds_off(lds);
  unsigned offA[4], offB[4];
#pragma unroll
  for (int m = 0; m < 4; ++m) {
    int r = wm * 64 + m * 16 + ln;
    int Ln = r >> 1, p = ((r & 1) * 4 + lg) ^ (Ln & 7);
    offA[m] = (unsigned)((Ln * 64 + p * 8) * 2);
  }
#pragma unroll
  for (int n = 0; n < 4; ++n) {
    int r = wn * 64 + n * 16 + ln;
    int Ln = r >> 1, p = ((r & 1) * 4 + lg) ^ (Ln & 7);
    offB[n] = (unsigned)(8192 + (Ln * 64 + p * 8) * 2);
  }

  f32x4 acc[4][4] = {};

  for (int tp = 0; tp < nt; tp += 2) {
    asm volatile("s_waitcnt vmcnt(0)");
    __builtin_amdgcn_sched_barrier(0);
    __builtin_amdgcn_s_barrier();
    const unsigned bb0 = base0 + (unsigned)((tp & 3) * (BUFU * 2));
    const unsigned bb1 = base0 + (unsigned)(((tp + 1) & 3) * (BUFU * 2));
    bf16x8 af[4], bf[4], af2[4], bf2[4];
#pragma unroll
    for (int m = 0; m < 4; ++m) af[m] = ds_read16(bb0 + offA[m]);
#pragma unroll
    for (int n = 0; n < 4; ++n) bf[n] = ds_read16(bb0 + offB[n]);
#pragma unroll
    for (int m = 0; m < 4; ++m) af2[m] = ds_read16(bb1 + offA[m]);
#pragma unroll
    for (int n = 0; n < 4; ++n) bf2[n] = ds_read16(bb1 + offB[n]);
    if (tp + 2 < nt) stage(tp + 2);
    if (tp + 3 < nt) stage(tp + 3);
    asm volatile("s_waitcnt lgkmcnt(8)");
    __builtin_amdgcn_sched_barrier(0);
    __builtin_amdgcn_s_setprio(1);
#pragma unroll
    for (int m = 0; m < 4; ++m)
#pragma unroll
      for (int n = 0; n < 4; ++n)
        acc[m][n] = __builtin_amdgcn_mfma_f32_16x16x32_bf16(af[m], bf[n], acc[m][n], 0, 0, 0);
    __builtin_amdgcn_s_setprio(0);
    asm volatile("s_waitcnt lgkmcnt(0)");
    __builtin_amdgcn_sched_barrier(0);
    __builtin_amdgcn_s_setprio(1);
#pragma unroll
    for (int m = 0; m < 4; ++m)
#pragma unroll
      for (int n = 0; n < 4; ++n)
        acc[m][n] = __builtin_amdgcn_mfma_f32_16x16x32_bf16(af2[m], bf2[n], acc[m][n], 0, 0, 0);
    __builtin_amdgcn_s_setprio(0);
  }

  __builtin_amdgcn_s_barrier();
  const unsigned ew = base0 + (unsigned)(w * 8192);
  const int col0 = n0 + wn * 64;
  const int rowbase = m0 + wm * 64;
  if (col0 < 2 * D_) {
    const float scl = (col0 < D_) ? QSCL : 1.0f;
    unsigned short* dst = (col0 < D_) ? outB : outB2;
    const int cb = (col0 < D_) ? col0 : col0 - D_;
    store_tile_coalesced(acc, ew, lane, lg, ln, dst, (size_t)D_,
                         rowbase, cb, false, scl);
  } else {
    const int cb = col0 - 2 * D_;
    const int bb2 = rowbase >> 11;
    const int s0base = rowbase & (S_ - 1);
#pragma unroll
    for (int m = 0; m < 4; ++m) {
#pragma unroll
      for (int n = 0; n < 4; ++n) {
        int col = cb + n * 16 + ln;
        ushort4 pk;
        pk.x = bf16r(acc[m][n][0]);
        pk.y = bf16r(acc[m][n][1]);
        pk.z = bf16r(acc[m][n][2]);
        pk.w = bf16r(acc[m][n][3]);
        *reinterpret_cast<ushort4*>(
            &outB3[((size_t)(bb2 * D_) + col) * S_ + s0base + lg * 4 + m * 16]) = pk;
      }
    }
  }
}

// ======== 128x128 / 512-thr / NBUF=4 PAIRED GEMM (wo/ffn2, +resid->fp32) ====
// Same proven sync ledger as qkv paired kernel: one vmcnt(0)+barrier per
// K-tile PAIR; stages write bufs (tp+2)&3,(tp+3)&3 (disjoint from read bufs);
// lgkm(6) between MFMA clusters (= tile-1's 6 reads outstanding).
__device__ __forceinline__ void gemm128p_body(
    const unsigned short* __restrict__ A, const unsigned short* __restrict__ Bw,
    int M, int N, int K,
    const float* __restrict__ resid, float* __restrict__ outF) {
  constexpr int BUFU = 8192;  // A 4096 + B 4096 ushorts (16 KB)
  __shared__ __attribute__((aligned(16))) unsigned short lds[4 * BUFU];  // 64 KB
  const int t = threadIdx.x, lane = t & 63, w = t >> 6;
  const int wm = w >> 2, wn = w & 3;
  const int lg = lane >> 4, ln = lane & 15;

  const int gx = gridDim.x;
  int bid = blockIdx.y * gx + blockIdx.x;
  int RX = gx >> 2, RY = gridDim.y >> 1;
  int xcd = bid & 7, c = bid >> 3;
  int bx = (xcd & 3) * RX + (c % RX);
  int by = (xcd >> 2) * RY + (c / RX);
  const int m0 = by * 128, n0 = bx * 128;

  const int nt = K >> 5;  // even (32 or 128)

  auto stage = [&](int tile) {
    const int buf = tile & 3;
    const int k0 = tile << 5;
    unsigned short* la = &lds[buf * BUFU];
    unsigned short* lb = la + 4096;
    int Ln = t >> 3, p = t & 7, u = p ^ (Ln & 7);
    int row = 2 * Ln + (u >> 2), cg = u & 3;
    gload_lds16(A + (size_t)(m0 + row) * K + k0 + cg * 8, &la[t * 8]);
    gload_lds16(Bw + (size_t)(n0 + row) * K + k0 + cg * 8, &lb[t * 8]);
  };

  stage(0);
  stage(1);

  const unsigned base0 = lds_off(lds);
  unsigned offA[4], offB[2];
#pragma unroll
  for (int m = 0; m < 4; ++m) {
    int r = wm * 64 + m * 16 + ln;
    int Ln = r >> 1, p = ((r & 1) * 4 + lg) ^ (Ln & 7);
    offA[m] = (unsigned)((Ln * 64 + p * 8) * 2);
  }
#pragma unroll
  for (int n = 0; n < 2; ++n) {
    int r = wn * 32 + n * 16 + ln;
    int Ln = r >> 1, p = ((r & 1) * 4 + lg) ^ (Ln & 7);
    offB[n] = (unsigned)(8192 + (Ln * 64 + p * 8) * 2);
  }

  f32x4 acc[4][2] = {};

  for (int tp = 0; tp < nt; tp += 2) {
    asm volatile("s_waitcnt vmcnt(0)");
    __builtin_amdgcn_sched_barrier(0);
    __builtin_amdgcn_s_barrier();
    const unsigned bb0 = base0 + (unsigned)((tp & 3) * (BUFU * 2));
    const unsigned bb1 = base0 + (unsigned)(((tp + 1) & 3) * (BUFU * 2));
    bf16x8 af[4], bf[2], af2[4], bf2[2];
#pragma unroll
    for (int m = 0; m < 4; ++m) af[m] = ds_read16(bb0 + offA[m]);
#pragma unroll
    for (int n = 0; n < 2; ++n) bf[n] = ds_read16(bb0 + offB[n]);
#pragma unroll
    for (int m = 0; m < 4; ++m) af2[m] = ds_read16(bb1 + offA[m]);
#pragma unroll
    for (int n = 0; n < 2; ++n) bf2[n] = ds_read16(bb1 + offB[n]);
    if (tp + 2 < nt) stage(tp + 2);
    if (tp + 3 < nt) stage(tp + 3);
    asm volatile("s_waitcnt lgkmcnt(6)");
    __builtin_amdgcn_sched_barrier(0);
    __builtin_amdgcn_s_setprio(1);
#pragma unroll
    for (int m = 0; m < 4; ++m)
#pragma unroll
      for (int n = 0; n < 2; ++n)
        acc[m][n] = __builtin_amdgcn_mfma_f32_16x16x32_bf16(af[m], bf[n], acc[m][n], 0, 0, 0);
    __builtin_amdgcn_s_setprio(0);
    asm volatile("s_waitcnt lgkmcnt(0)");
    __builtin_amdgcn_sched_barrier(0);
    __builtin_amdgcn_s_setprio(1);
#pragma unroll
    for (int m = 0; m < 4; ++m)
#pragma unroll
      for (int n = 0; n < 2; ++n)
        acc[m][n] = __builtin_amdgcn_mfma_f32_16x16x32_bf16(af2[m], bf2[n], acc[m][n], 0, 0, 0);
    __builtin_amdgcn_s_setprio(0);
  }

  const int rbase = m0 + wm * 64 + lg * 4;
  const int cbase = n0 + wn * 32 + ln;
#pragma unroll
  for (int m = 0; m < 4; ++m) {
#pragma unroll
    for (int n = 0; n < 2; ++n) {
      int col = cbase + n * 16;
#pragma unroll
      for (int j = 0; j < 4; ++j) {
        int row = rbase + m * 16 + j;
        outF[(size_t)row * N + col] = acc[m][n][j] + resid[(size_t)row * N + col];
      }
    }
  }
}

__global__ __launch_bounds__(512, 4) void wo_gemm(
    const unsigned short* __restrict__ A, const unsigned short* __restrict__ Bw,
    int M, int N, int K, const float* __restrict__ resid, float* __restrict__ outF) {
  gemm128p_body(A, Bw, M, N, K, resid, outF);
}
__global__ __launch_bounds__(512, 4) void ffn2_gemm(
    const unsigned short* __restrict__ A, const unsigned short* __restrict__ Bw,
    int M, int N, int K, const float* __restrict__ resid, float* __restrict__ outF) {
  gemm128p_body(A, Bw, M, N, K, resid, outF);
}

// ---------------- Flash attention: KVBLK=128, paired q-tiles, pipelined DS --
#define PV_ISSUE(c, pa, v0, v1, v2, v3) do {                                   \
  unsigned cg_ = (unsigned)(((((c) * 4) + lg) ^ ln) & 15);                     \
  pa = ds_read16(pbase + (unsigned)(ln * 256) + cg_ * 16);                     \
  v0 = ds_read16(vb + (unsigned)((0 * 16 + ln) * 256) + cg_ * 16);             \
  v1 = ds_read16(vb + (unsigned)((1 * 16 + ln) * 256) + cg_ * 16);             \
  v2 = ds_read16(vb + (unsigned)((2 * 16 + ln) * 256) + cg_ * 16);             \
  v3 = ds_read16(vb + (unsigned)((3 * 16 + ln) * 256) + cg_ * 16);             \
} while (0)

#define PV_MFMA(pa, v0, v1, v2, v3) do {                                       \
  oacc[0] = __builtin_amdgcn_mfma_f32_16x16x32_bf16(pa, v0, oacc[0], 0, 0, 0); \
  oacc[1] = __builtin_amdgcn_mfma_f32_16x16x32_bf16(pa, v1, oacc[1], 0, 0, 0); \
  oacc[2] = __builtin_amdgcn_mfma_f32_16x16x32_bf16(pa, v2, oacc[2], 0, 0, 0); \
  oacc[3] = __builtin_amdgcn_mfma_f32_16x16x32_bf16(pa, v3, oacc[3], 0, 0, 0); \
} while (0)

__global__ __launch_bounds__(256, 2) void attn_kernel(
    const unsigned short* __restrict__ qg, const unsigned short* __restrict__ kg,
    const unsigned short* __restrict__ vt, unsigned short* __restrict__ og) {
  __shared__ __attribute__((aligned(16))) unsigned short Kl[2][8192];
  __shared__ __attribute__((aligned(16))) unsigned short Vl[2][8192];
  __shared__ __attribute__((aligned(16))) unsigned short Pl[4][2048];
  const int t = threadIdx.x, lane = t & 63, w = t >> 6;
  const int lg = lane >> 4, ln = lane & 15;

  int bid = blockIdx.x;
  int nl = (bid & 7) * 64 + (bid >> 3);
  int bh = nl >> 4, pi = nl & 15;
  int b = bh >> 4, h = bh & 15;

  const unsigned kbase = lds_off(&Kl[0][0]);
  const unsigned vbase = lds_off(&Vl[0][0]);
  const unsigned pbase = lds_off(&Pl[w][0]);

  auto runq = [&](int qtile, bool first) {
    const int q0 = qtile * 64;
    const int qw = q0 + w * 16;
    const int nt = (q0 >> 7) + 1;

    bf16x8 aq[2];
    {
      const unsigned short* qp =
          qg + (size_t)(b * S_ + qw + ln) * D_ + h * DK_ + lg * 8;
      aq[0] = *reinterpret_cast<const bf16x8*>(qp);
      aq[1] = *reinterpret_cast<const bf16x8*>(qp + 32);
    }
    asm volatile("" : : "v"(aq[0]), "v"(aq[1]));

    float mr = -1e30f, lr = 0.f;
    f32x4 oacc[4] = {};

    auto stage = [&](int kt) {
      const int buf = kt & 1;
      const int kv0 = kt * 128;
#pragma unroll
      for (int i = 0; i < 4; ++i) {
        int g = i * 256 + t;
        int row = g >> 3, cg = g & 7, sg = cg ^ (row & 7);
        gload_lds16(kg + (size_t)(b * S_ + kv0 + row) * D_ + h * DK_ + sg * 8,
                    &Kl[buf][g * 8]);
      }
#pragma unroll
      for (int i = 0; i < 4; ++i) {
        int g = i * 256 + t;
        int row = g >> 4, cg = g & 15, sg = cg ^ (row & 15);
        gload_lds16(vt + (size_t)(b * D_ + h * DK_ + row) * S_ + kv0 + sg * 8,
                    &Vl[buf][g * 8]);
      }
    };

    if (!first) __builtin_amdgcn_s_barrier();
    stage(0);

    auto ctile = [&](int kt, bool dm) {
      const unsigned kb = kbase + (unsigned)((kt & 1) * 16384);
      const unsigned vb = vbase + (unsigned)((kt & 1) * 16384);
      f32x4 sc[8] = {};
      bf16x8 kf[8], kf2[8];
#pragma unroll
      for (int n = 0; n < 8; ++n) {
        int r = n * 16 + ln;
        int cg0 = lg ^ (r & 7);
        kf[n] = ds_read16(kb + (unsigned)((r * 128 + cg0 * 16)));
      }
#pragma unroll
      for (int n = 0; n < 8; ++n) {
        int r = n * 16 + ln;
        int cg1 = (4 + lg) ^ (r & 7);
        kf2[n] = ds_read16(kb + (unsigned)((r * 128 + cg1 * 16)));
      }
      if (!dm) stage(kt + 1);
      asm volatile("s_waitcnt lgkmcnt(8)");
      __builtin_amdgcn_sched_barrier(0);
#pragma unroll
      for (int n = 0; n < 8; ++n)
        sc[n] = __builtin_amdgcn_mfma_f32_16x16x32_bf16(kf[n], aq[0], sc[n], 0, 0, 0);
      asm volatile("s_waitcnt lgkmcnt(0)");
      __builtin_amdgcn_sched_barrier(0);
#pragma unroll
      for (int n = 0; n < 8; ++n)
        sc[n] = __builtin_amdgcn_mfma_f32_16x16x32_bf16(kf2[n], aq[1], sc[n], 0, 0, 0);
      if (dm) {
        const int kv0 = kt * 128;
        const int qi = qw + ln;
#pragma unroll
        for (int n = 0; n < 8; ++n)
#pragma unroll
          for (int j = 0; j < 4; ++j)
            if ((kv0 + n * 16 + lg * 4 + j) > qi) sc[n][j] = -1e30f;
      }
      float mx = -1e30f;
#pragma unroll
      for (int n = 0; n < 8; ++n) {
        float a = fmaxf(fmaxf(sc[n][0], sc[n][1]), fmaxf(sc[n][2], sc[n][3]));
        mx = fmaxf(mx, a);
      }
      mx = fmaxf(mx, __shfl_xor(mx, 16));
      mx = fmaxf(mx, __shfl_xor(mx, 32));
      float mn = fmaxf(mr, mx);
      float ps = 0.f;
#pragma unroll
      for (int n = 0; n < 8; ++n)
#pragma unroll
        for (int j = 0; j < 4; ++j) {
          float p = fexp2(sc[n][j] - mn);
          sc[n][j] = p;
          ps += p;
        }
      if (__all(mx <= mr)) {
        lr += ps;
      } else {
        float sf = fexp2(mr - mn);
        mr = mn;
        lr = lr * sf + ps;
#pragma unroll
        for (int j = 0; j < 4; ++j) {
          float sfj = __shfl(sf, lg * 4 + j);
#pragma unroll
          for (int f = 0; f < 4; ++f) oacc[f][j] *= sfj;
        }
      }
#pragma unroll
      for (int n = 0; n < 8; ++n) {
        int kvc = n * 16 + lg * 4;
        int gsw = ((kvc >> 3) ^ ln) & 15;
        unsigned pa_addr = pbase + (unsigned)(ln * 256 + gsw * 16 + (kvc & 7) * 2);
        ds_write32(pa_addr, cvt_pk_bf16(sc[n][0], sc[n][1]));
        ds_write32(pa_addr + 4, cvt_pk_bf16(sc[n][2], sc[n][3]));
      }
      asm volatile("s_waitcnt lgkmcnt(0)");
      __builtin_amdgcn_sched_barrier(0);
      bf16x8 paA, vA0, vA1, vA2, vA3, paB, vB0, vB1, vB2, vB3;
      PV_ISSUE(0, paA, vA0, vA1, vA2, vA3);
      PV_ISSUE(1, paB, vB0, vB1, vB2, vB3);
      asm volatile("s_waitcnt lgkmcnt(5)");
      __builtin_amdgcn_sched_barrier(0);
      PV_MFMA(paA, vA0, vA1, vA2, vA3);
      PV_ISSUE(2, paA, vA0, vA1, vA2, vA3);
      asm volatile("s_waitcnt lgkmcnt(5)");
      __builtin_amdgcn_sched_barrier(0);
      PV_MFMA(paB, vB0, vB1, vB2, vB3);
      PV_ISSUE(3, paB, vB0, vB1, vB2, vB3);
      asm volatile("s_waitcnt lgkmcnt(5)");
      __builtin_amdgcn_sched_barrier(0);
      PV_MFMA(paA, vA0, vA1, vA2, vA3);
      asm volatile("s_waitcnt lgkmcnt(0)");
      __builtin_amdgcn_sched_barrier(0);
      PV_MFMA(paB, vB0, vB1, vB2, vB3);
    };

    for (int kt = 0; kt < nt - 1; ++kt) {
      asm volatile("s_waitcnt vmcnt(0)");
      __builtin_amdgcn_sched_barrier(0);
      __builtin_amdgcn_s_barrier();
      ctile(kt, false);
    }
    asm volatile("s_waitcnt vmcnt(0)");
    __builtin_amdgcn_sched_barrier(0);
    __builtin_amdgcn_s_barrier();
    ctile(nt - 1, true);

    lr += __shfl_xor(lr, 16);
    lr += __shfl_xor(lr, 32);
#pragma unroll
    for (int j = 0; j < 4; ++j) {
      float lj = __shfl(lr, lg * 4 + j);
      float inv = 1.0f / lj;
      int row = b * S_ + qw + lg * 4 + j;
#pragma unroll
      for (int f = 0; f < 4; ++f)
        og[(size_t)row * D_ + h * DK_ + f * 16 + ln] = bf16r(oacc[f][j] * inv);
    }
  };

  runq(31 - pi, true);
  runq(pi, false);
}

// ---------------- launch ----------------
extern "C" void kernel_launch(void* const* d_in, const int* in_sizes, int n_in,
                              void* d_out, int out_size, void* d_ws, size_t ws_size,
                              hipStream_t stream) {
  const float* x  = (const float*)d_in[0];
  const float* wq = (const float*)d_in[1];
  const float* wk = (const float*)d_in[2];
  const float* wv = (const float*)d_in[3];
  const float* wo = (const float*)d_in[4];
  const float* w1 = (const float*)d_in[5];
  const float* w2 = (const float*)d_in[6];
  const float* g1 = (const float*)d_in[7];
  const float* g2 = (const float*)d_in[8];
  float* out = (float*)d_out;

  char* ws = (char*)d_ws;
  const size_t MB = 1024 * 1024;
  unsigned short* wqkv_b = (unsigned short*)(ws + 0 * MB);   // [3072][1024]
  unsigned short* wo_b   = (unsigned short*)(ws + 6 * MB);
  unsigned short* w1_b   = (unsigned short*)(ws + 8 * MB);
  unsigned short* w2_b   = (unsigned short*)(ws + 16 * MB);
  unsigned short* h_b    = (unsigned short*)(ws + 24 * MB);
  unsigned short* q_b    = (unsigned short*)(ws + 32 * MB);
  unsigned short* k_b    = (unsigned short*)(ws + 40 * MB);
  unsigned short* vt_b   = (unsigned short*)(ws + 48 * MB);
  unsigned short* o_b    = (unsigned short*)(ws + 56 * MB);
  float*          x1     = (float*)(ws + 64 * MB);
  unsigned short* mid    = (unsigned short*)(ws + 80 * MB);

  CvtArgs ca;
  ca.src[0] = wq; ca.dst[0] = wqkv_b;
  ca.src[1] = wk; ca.dst[1] = wqkv_b + (size_t)D_ * D_;
  ca.src[2] = wv; ca.dst[2] = wqkv_b + (size_t)2 * D_ * D_;
  ca.src[3] = wo; ca.dst[3] = wo_b;
  ca.src[4] = w1; ca.dst[4] = w1_b;
  ca.src[5] = w2; ca.dst[5] = w2_b;
  int q4 = D_ * D_ / 4, f4 = F_ * D_ / 4;
  ca.start[0] = 0;
  ca.start[1] = q4;
  ca.start[2] = 2 * q4;
  ca.start[3] = 3 * q4;
  ca.start[4] = 4 * q4;
  ca.start[5] = 4 * q4 + f4;
  ca.start[6] = 4 * q4 + 2 * f4;
  cvt_all_kernel<<<(ca.start[6] + 255) / 256, 256, 0, stream>>>(ca);

  rmsnorm_kernel<<<NTOK, 256, 0, stream>>>(x, g1, h_b);

  // fused QKV: N=3072, paired-K 128^2 / 256 thr, grid 24x32 (768 blocks)
  qkv_gemm<<<dim3(3 * D_ / 128, NTOK / 128), dim3(256), 0, stream>>>(
      h_b, wqkv_b, NTOK, 3 * D_, D_, q_b, k_b, vt_b);

  attn_kernel<<<dim3(512), dim3(256), 0, stream>>>(q_b, k_b, vt_b, o_b);

  // WO + residual: N=1024, paired-K 128^2 / 512 thr, grid 8x32
  wo_gemm<<<dim3(D_ / 128, NTOK / 128), dim3(512), 0, stream>>>(
      o_b, wo_b, NTOK, D_, D_, x, x1);

  rmsnorm_kernel<<<NTOK, 256, 0, stream>>>(x1, g2, h_b);

  // FFN1 + fast GELU: N=4096, 256^2 BK=64 8-phase, grid 16x16 (256 blocks)
  ffn1_gemm<<<dim3(F_ / 256, NTOK / 256), dim3(512), 0, stream>>>(
      h_b, w1_b, NTOK, F_, D_, mid);

  // FFN2 + residual: N=1024, paired-K 128^2 / 512 thr, grid 8x32
  ffn2_gemm<<<dim3(D_ / 128, NTOK / 128), dim3(512), 0, stream>>>(
      mid, w2_b, NTOK, D_, F_, x1, out);
}

// Round 20
// 202.706 us; speedup vs baseline: 1.0529x; 1.0529x over previous
//
#include <hip/hip_runtime.h>
#include <hip/hip_bf16.h>
#include <math.h>

#define B_   2
#define S_   2048
#define D_   1024
#define H_   16
#define DK_  64
#define F_   4096
#define NTOK (B_ * S_)

typedef __bf16 bf16x8 __attribute__((ext_vector_type(8)));
typedef float  f32x4  __attribute__((ext_vector_type(4)));

__device__ __forceinline__ unsigned short bf16r(float f) {
  unsigned u = __builtin_bit_cast(unsigned, f);
  u += 0x7fffu + ((u >> 16) & 1u);
  return (unsigned short)(u >> 16);
}

__device__ __forceinline__ void gload_lds16(const void* g, void* l) {
  __builtin_amdgcn_global_load_lds(
      (__attribute__((address_space(1))) void*)g,
      (__attribute__((address_space(3))) void*)l, 16, 0, 0);
}

__device__ __forceinline__ unsigned lds_off(void* p) {
  return (unsigned)(size_t)(__attribute__((address_space(3))) void*)p;
}
__device__ __forceinline__ bf16x8 ds_read16(unsigned a) {
  bf16x8 r;
  asm volatile("ds_read_b128 %0, %1" : "=v"(r) : "v"(a));
  return r;
}
__device__ __forceinline__ void ds_write32(unsigned a, unsigned v) {
  asm volatile("ds_write_b32 %0, %1" : : "v"(a), "v"(v));
}
__device__ __forceinline__ void ds_write16b(unsigned a, unsigned v) {
  asm volatile("ds_write_b16 %0, %1" : : "v"(a), "v"(v));
}
__device__ __forceinline__ float fexp2(float x) {
  float r;
  asm volatile("v_exp_f32 %0, %1\n\ts_nop 0" : "=v"(r) : "v"(x));
  return r;
}
__device__ __forceinline__ unsigned cvt_pk_bf16(float lo, float hi) {
  unsigned r;
  asm volatile("v_cvt_pk_bf16_f32 %0, %1, %2" : "=v"(r) : "v"(lo), "v"(hi));
  return r;
}

__device__ __forceinline__ float gelu_fast(float x) {
  float y = 0.7978845608f * x * (1.0f + 0.044715f * x * x);
  float e = fexp2(2.885390082f * y);
  float t = 1.0f - 2.0f / (e + 1.0f);
  return 0.5f * x * (1.0f + t);
}

#define QSCL 0.18033688f  /* (1/8) * log2(e), folded into Q at QKV epilogue */

// ---------------- all weights fp32 -> bf16, one launch ----------------
struct CvtArgs {
  const float* src[6];
  unsigned short* dst[6];
  int start[7];
};
__global__ __launch_bounds__(256) void cvt_all_kernel(CvtArgs a) {
  int i = blockIdx.x * blockDim.x + threadIdx.x;
  if (i >= a.start[6]) return;
  int k = 0;
#pragma unroll
  for (int j = 1; j < 6; ++j)
    if (i >= a.start[j]) k = j;
  int off = i - a.start[k];
  float4 v = reinterpret_cast<const float4*>(a.src[k])[off];
  ushort4 o;
  o.x = bf16r(v.x); o.y = bf16r(v.y); o.z = bf16r(v.z); o.w = bf16r(v.w);
  reinterpret_cast<ushort4*>(a.dst[k])[off] = o;
}

// ---------------- RMSNorm (fp32 in, bf16 out) ----------------
__global__ __launch_bounds__(256) void rmsnorm_kernel(
    const float* __restrict__ x, const float* __restrict__ g,
    unsigned short* __restrict__ out) {
  int row = blockIdx.x;
  int t = threadIdx.x, lane = t & 63, w = t >> 6;
  float4 v = reinterpret_cast<const float4*>(x + (size_t)row * D_)[t];
  float ss = v.x * v.x + v.y * v.y + v.z * v.z + v.w * v.w;
#pragma unroll
  for (int d = 1; d < 64; d <<= 1) ss += __shfl_xor(ss, d);
  __shared__ float red[4];
  if (lane == 0) red[w] = ss;
  __syncthreads();
  float tot = red[0] + red[1] + red[2] + red[3];
  float rstd = rsqrtf(tot * (1.0f / D_) + 1e-5f);
  float4 gv = reinterpret_cast<const float4*>(g)[t];
  ushort4 o;
  o.x = bf16r(v.x * rstd * gv.x);
  o.y = bf16r(v.y * rstd * gv.y);
  o.z = bf16r(v.z * rstd * gv.z);
  o.w = bf16r(v.w * rstd * gv.w);
  reinterpret_cast<ushort4*>(out + (size_t)row * D_)[t] = o;
}

// wave-tile (64x64) LDS-staged coalesced bf16 store (proven round 15)
__device__ __forceinline__ void store_tile_coalesced(
    const f32x4 (&acc)[4][4], unsigned ew, int lane, int lg, int ln,
    unsigned short* __restrict__ dst, size_t stride, int rowbase, int colbase,
    bool gelu, float scl) {
#pragma unroll
  for (int m = 0; m < 4; ++m)
#pragma unroll
    for (int n = 0; n < 4; ++n)
#pragma unroll
      for (int j = 0; j < 4; ++j) {
        int lrow = lg * 4 + m * 16 + j;
        int lcol = n * 16 + ln;
        int g = (lcol >> 3) ^ (lrow & 7);
        float v = acc[m][n][j];
        if (gelu) v = gelu_fast(v);
        ds_write16b(ew + (unsigned)((lrow * 64 + g * 8 + (lcol & 7)) * 2),
                    (unsigned)bf16r(v * scl));
      }
  asm volatile("s_waitcnt lgkmcnt(0)");
  __builtin_amdgcn_sched_barrier(0);
  bf16x8 cv[8];
#pragma unroll
  for (int i = 0; i < 8; ++i) {
    int lrow = i * 8 + (lane >> 3);
    int g = (lane & 7) ^ (lrow & 7);
    cv[i] = ds_read16(ew + (unsigned)((lrow * 64 + g * 8) * 2));
  }
  asm volatile("s_waitcnt lgkmcnt(0)");
  __builtin_amdgcn_sched_barrier(0);
#pragma unroll
  for (int i = 0; i < 8; ++i) {
    int lrow = i * 8 + (lane >> 3);
    *reinterpret_cast<bf16x8*>(
        &dst[(size_t)(rowbase + lrow) * stride + colbase + (lane & 7) * 8]) = cv[i];
  }
}

// ======== ffn1: 256x256 / BK=64 / 8-wave / 2-buf 8-phase schedule (m201) ====
__global__ __launch_bounds__(512, 2) void ffn1_gemm(
    const unsigned short* __restrict__ A, const unsigned short* __restrict__ Bw,
    int M, int N, int K, unsigned short* __restrict__ outB) {
  __shared__ __attribute__((aligned(16))) unsigned short lds[65536];  // 128 KB
  const int t = threadIdx.x, lane = t & 63, w = t >> 6;
  const int wm = w >> 2, wn = w & 3;
  const int lg = lane >> 4, ln = lane & 15;

  const int gx = gridDim.x;  // 16
  int bid = blockIdx.y * gx + blockIdx.x;
  int xcd = bid & 7, c = bid >> 3;
  int RX = gx >> 2, RY = gridDim.y >> 1;
  int bx = (xcd & 3) * RX + (c % RX);
  int by = (xcd >> 2) * RY + (c / RX);
  const int m0 = by * 256, n0 = bx * 256;

  const int nt = K >> 6;      // 16 K-tiles of 64
  const int niter = nt >> 1;  // 8

  auto SA = [&](int tile, int h) {
    unsigned short* dst = &lds[(tile & 1) * 32768 + h * 8192];
    const int k0 = tile << 6;
    const int rb = m0 + h * 128;
#pragma unroll
    for (int i = 0; i < 2; ++i) {
      int g = i * 512 + t;
      int row = g >> 3, sg = (g & 7) ^ (row & 7);
      gload_lds16(A + (size_t)(rb + row) * K + k0 + sg * 8, &dst[g * 8]);
    }
  };
  auto SB = [&](int tile, int h) {
    unsigned short* dst = &lds[(tile & 1) * 32768 + 16384 + h * 8192];
    const int k0 = tile << 6;
    const int rb = n0 + h * 128;
#pragma unroll
    for (int i = 0; i < 2; ++i) {
      int g = i * 512 + t;
      int row = g >> 3, sg = (g & 7) ^ (row & 7);
      gload_lds16(Bw + (size_t)(rb + row) * K + k0 + sg * 8, &dst[g * 8]);
    }
  };

  SA(0, 0); SA(0, 1); SB(0, 0); SB(0, 1); SB(1, 0); SB(1, 1);

  const unsigned base0 = lds_off(lds);
  unsigned offA[8], offB[4];
#pragma unroll
  for (int m = 0; m < 8; ++m) {
    int r = wm * 128 + m * 16 + ln;
    offA[m] = (unsigned)(r * 128 + (lg ^ (r & 7)) * 16);
  }
#pragma unroll
  for (int n = 0; n < 4; ++n) {
    int r = wn * 64 + n * 16 + ln;
    offB[n] = (unsigned)(32768 + r * 128 + (lg ^ (r & 7)) * 16);
  }

  f32x4 acc[8][4] = {};

  asm volatile("s_waitcnt vmcnt(0)");
  __builtin_amdgcn_sched_barrier(0);
  __builtin_amdgcn_s_barrier();

  for (int it = 0; it < niter; ++it) {
    const int t0 = 2 * it, t1 = 2 * it + 1;
    const bool more = (it + 1 < niter);
    const unsigned bb0 = base0 + (unsigned)((t0 & 1) * 65536);
    const unsigned bb1 = base0 + (unsigned)((t1 & 1) * 65536);
    bf16x8 bfr[4][2];
#pragma unroll
    for (int q = 0; q < 4; ++q) {
      bf16x8 af[2][2];
      if (q == 0) {
#pragma unroll
        for (int n = 0; n < 4; ++n) {
          bfr[n][0] = ds_read16(bb0 + offB[n]);
          bfr[n][1] = ds_read16(bb0 + (offB[n] ^ 0x40u));
        }
      }
#pragma unroll
      for (int mm = 0; mm < 2; ++mm) {
        af[mm][0] = ds_read16(bb0 + offA[2 * q + mm]);
        af[mm][1] = ds_read16(bb0 + (offA[2 * q + mm] ^ 0x40u));
      }
      if (q == 0)       SA(t1, 0);
      else if (q == 1)  SA(t1, 1);
      else if (q == 2)  { if (more) SB(t0 + 2, 0); }
      else              { if (more) SB(t0 + 2, 1); }
      if (q == 3) {
        if (more) { asm volatile("s_waitcnt vmcnt(4)"); }
        else      { asm volatile("s_waitcnt vmcnt(0)"); }
        __builtin_amdgcn_sched_barrier(0);
      }
      __builtin_amdgcn_s_barrier();
      asm volatile("s_waitcnt lgkmcnt(0)");
      __builtin_amdgcn_sched_barrier(0);
      __builtin_amdgcn_s_setprio(1);
#pragma unroll
      for (int mm = 0; mm < 2; ++mm)
#pragma unroll
        for (int n = 0; n < 4; ++n) {
          acc[2 * q + mm][n] = __builtin_amdgcn_mfma_f32_16x16x32_bf16(
              af[mm][0], bfr[n][0], acc[2 * q + mm][n], 0, 0, 0);
          acc[2 * q + mm][n] = __builtin_amdgcn_mfma_f32_16x16x32_bf16(
              af[mm][1], bfr[n][1], acc[2 * q + mm][n], 0, 0, 0);
        }
      __builtin_amdgcn_s_setprio(0);
      __builtin_amdgcn_s_barrier();
    }
#pragma unroll
    for (int q = 0; q < 4; ++q) {
      bf16x8 af[2][2];
      if (q == 0) {
#pragma unroll
        for (int n = 0; n < 4; ++n) {
          bfr[n][0] = ds_read16(bb1 + offB[n]);
          bfr[n][1] = ds_read16(bb1 + (offB[n] ^ 0x40u));
        }
      }
#pragma unroll
      for (int mm = 0; mm < 2; ++mm) {
        af[mm][0] = ds_read16(bb1 + offA[2 * q + mm]);
        af[mm][1] = ds_read16(bb1 + (offA[2 * q + mm] ^ 0x40u));
      }
      if (more) {
        if (q == 0)      SA(t0 + 2, 0);
        else if (q == 1) SA(t0 + 2, 1);
        else if (q == 2) SB(t1 + 2, 0);
        else             SB(t1 + 2, 1);
      }
      if (q == 3) {
        if (more) { asm volatile("s_waitcnt vmcnt(4)"); }
        else      { asm volatile("s_waitcnt vmcnt(0)"); }
        __builtin_amdgcn_sched_barrier(0);
      }
      __builtin_amdgcn_s_barrier();
      asm volatile("s_waitcnt lgkmcnt(0)");
      __builtin_amdgcn_sched_barrier(0);
      __builtin_amdgcn_s_setprio(1);
#pragma unroll
      for (int mm = 0; mm < 2; ++mm)
#pragma unroll
        for (int n = 0; n < 4; ++n) {
          acc[2 * q + mm][n] = __builtin_amdgcn_mfma_f32_16x16x32_bf16(
              af[mm][0], bfr[n][0], acc[2 * q + mm][n], 0, 0, 0);
          acc[2 * q + mm][n] = __builtin_amdgcn_mfma_f32_16x16x32_bf16(
              af[mm][1], bfr[n][1], acc[2 * q + mm][n], 0, 0, 0);
        }
      __builtin_amdgcn_s_setprio(0);
      __builtin_amdgcn_s_barrier();
    }
  }

  const unsigned ew = base0 + (unsigned)(w * 8192);
  store_tile_coalesced(*reinterpret_cast<const f32x4(*)[4][4]>(&acc[0]),
                       ew, lane, lg, ln, outB, (size_t)N,
                       m0 + wm * 128, n0 + wn * 64, true, 1.0f);
  store_tile_coalesced(*reinterpret_cast<const f32x4(*)[4][4]>(&acc[4]),
                       ew, lane, lg, ln, outB, (size_t)N,
                       m0 + wm * 128 + 64, n0 + wn * 64, true, 1.0f);
}

// ======== 128x128 / 256-thr / NBUF=4 PAIRED GEMM (qkv, round-16 winner) =====
__global__ __launch_bounds__(256, 2) void qkv_gemm(
    const unsigned short* __restrict__ A, const unsigned short* __restrict__ Bw,
    int M, int N, int K,
    unsigned short* __restrict__ outB, unsigned short* __restrict__ outB2,
    unsigned short* __restrict__ outB3) {
  constexpr int BUFU = 8192;
  __shared__ __attribute__((aligned(16))) unsigned short lds[4 * BUFU];  // 64 KB
  const int t = threadIdx.x, lane = t & 63, w = t >> 6;
  const int wm = w >> 1, wn = w & 1;
  const int lg = lane >> 4, ln = lane & 15;

  const int gx = gridDim.x;
  int bid = blockIdx.y * gx + blockIdx.x;
  int xcd = bid & 7, c = bid >> 3;
  int RX = gx >> 2, RY = gridDim.y >> 1;
  int bx = (xcd & 3) * RX + (c % RX);
  int by = (xcd >> 2) * RY + (c / RX);
  const int m0 = by * 128, n0 = bx * 128;

  const int nt = K >> 5;  // even

  auto stage = [&](int tile) {
    int buf = tile & 3;
    const int k0 = tile << 5;
    unsigned short* la = &lds[buf * BUFU];
    unsigned short* lb = la + 4096;
#pragma unroll
    for (int i = 0; i < 2; ++i) {
      int g = i * 256 + t;
      int Ln = g >> 3, p = g & 7, u = p ^ (Ln & 7);
      int row = 2 * Ln + (u >> 2), cg = u & 3;
      gload_lds16(A + (size_t)(m0 + row) * K + k0 + cg * 8, &la[g * 8]);
    }
#pragma unroll
    for (int i = 0; i < 2; ++i) {
      int g = i * 256 + t;
      int Ln = g >> 3, p = g & 7, u = p ^ (Ln & 7);
      int row = 2 * Ln + (u >> 2), cg = u & 3;
      gload_lds16(Bw + (size_t)(n0 + row) * K + k0 + cg * 8, &lb[g * 8]);
    }
  };

  stage(0);
  stage(1);

  const unsigned base0 = lds_off(lds);
  unsigned offA[4], offB[4];
#pragma unroll
  for (int m = 0; m < 4; ++m) {
    int r = wm * 64 + m * 16 + ln;
    int Ln = r >> 1, p = ((r & 1) * 4 + lg) ^ (Ln & 7);
    offA[m] = (unsigned)((Ln * 64 + p * 8) * 2);
  }
#pragma unroll
  for (int n = 0; n < 4; ++n) {
    int r = wn * 64 + n * 16 + ln;
    int Ln = r >> 1, p = ((r & 1) * 4 + lg) ^ (Ln & 7);
    offB[n] = (unsigned)(8192 + (Ln * 64 + p * 8) * 2);
  }

  f32x4 acc[4][4] = {};

  for (int tp = 0; tp < nt; tp += 2) {
    asm volatile("s_waitcnt vmcnt(0)");
    __builtin_amdgcn_sched_barrier(0);
    __builtin_amdgcn_s_barrier();
    const unsigned bb0 = base0 + (unsigned)((tp & 3) * (BUFU * 2));
    const unsigned bb1 = base0 + (unsigned)(((tp + 1) & 3) * (BUFU * 2));
    bf16x8 af[4], bf[4], af2[4], bf2[4];
#pragma unroll
    for (int m = 0; m < 4; ++m) af[m] = ds_read16(bb0 + offA[m]);
#pragma unroll
    for (int n = 0; n < 4; ++n) bf[n] = ds_read16(bb0 + offB[n]);
#pragma unroll
    for (int m = 0; m < 4; ++m) af2[m] = ds_read16(bb1 + offA[m]);
#pragma unroll
    for (int n = 0; n < 4; ++n) bf2[n] = ds_read16(bb1 + offB[n]);
    if (tp + 2 < nt) stage(tp + 2);
    if (tp + 3 < nt) stage(tp + 3);
    asm volatile("s_waitcnt lgkmcnt(8)");
    __builtin_amdgcn_sched_barrier(0);
    __builtin_amdgcn_s_setprio(1);
#pragma unroll
    for (int m = 0; m < 4; ++m)
#pragma unroll
      for (int n = 0; n < 4; ++n)
        acc[m][n] = __builtin_amdgcn_mfma_f32_16x16x32_bf16(af[m], bf[n], acc[m][n], 0, 0, 0);
    __builtin_amdgcn_s_setprio(0);
    asm volatile("s_waitcnt lgkmcnt(0)");
    __builtin_amdgcn_sched_barrier(0);
    __builtin_amdgcn_s_setprio(1);
#pragma unroll
    for (int m = 0; m < 4; ++m)
#pragma unroll
      for (int n = 0; n < 4; ++n)
        acc[m][n] = __builtin_amdgcn_mfma_f32_16x16x32_bf16(af2[m], bf2[n], acc[m][n], 0, 0, 0);
    __builtin_amdgcn_s_setprio(0);
  }

  __builtin_amdgcn_s_barrier();
  const unsigned ew = base0 + (unsigned)(w * 8192);
  const int col0 = n0 + wn * 64;
  const int rowbase = m0 + wm * 64;
  if (col0 < 2 * D_) {
    const float scl = (col0 < D_) ? QSCL : 1.0f;
    unsigned short* dst = (col0 < D_) ? outB : outB2;
    const int cb = (col0 < D_) ? col0 : col0 - D_;
    store_tile_coalesced(acc, ew, lane, lg, ln, dst, (size_t)D_,
                         rowbase, cb, false, scl);
  } else {
    const int cb = col0 - 2 * D_;
    const int bb2 = rowbase >> 11;
    const int s0base = rowbase & (S_ - 1);
#pragma unroll
    for (int m = 0; m < 4; ++m) {
#pragma unroll
      for (int n = 0; n < 4; ++n) {
        int col = cb + n * 16 + ln;
        ushort4 pk;
        pk.x = bf16r(acc[m][n][0]);
        pk.y = bf16r(acc[m][n][1]);
        pk.z = bf16r(acc[m][n][2]);
        pk.w = bf16r(acc[m][n][3]);
        *reinterpret_cast<ushort4*>(
            &outB3[((size_t)(bb2 * D_) + col) * S_ + s0base + lg * 4 + m * 16]) = pk;
      }
    }
  }
}

// ======== 128x128 4-deep pipelined GEMM (N=1024 outputs, +resid->fp32) ======
// Round-18 proven: counted vmcnt(4)/(2) NEVER drains to 0 in steady state.
__device__ __forceinline__ void gemm128_body(
    const unsigned short* __restrict__ A, const unsigned short* __restrict__ Bw,
    int M, int N, int K,
    const float* __restrict__ resid, float* __restrict__ outF) {
  constexpr int BUFU = 256 * 32;
  __shared__ __attribute__((aligned(16))) unsigned short lds[4 * BUFU];
  const int t = threadIdx.x, lane = t & 63, w = t >> 6;
  const int wm = w >> 2, wn = w & 3;
  const int lg = lane >> 4, ln = lane & 15;

  const int gx = gridDim.x;
  int bid = blockIdx.y * gx + blockIdx.x;
  int RX = gx >> 2, RY = gridDim.y >> 1;
  int xcd = bid & 7, c = bid >> 3;
  int bx = (xcd & 3) * RX + (c % RX);
  int by = (xcd >> 2) * RY + (c / RX);
  const int m0 = by * 128, n0 = bx * 128;

  const int nt = K >> 5;

  auto stage = [&](int tile) {
    const int buf = tile & 3;
    const int k0 = tile << 5;
    unsigned short* la = &lds[buf * BUFU];
    unsigned short* lb = la + 4096;
    int Ln = t >> 3, p = t & 7, u = p ^ (Ln & 7);
    int row = 2 * Ln + (u >> 2), cg = u & 3;
    gload_lds16(A + (size_t)(m0 + row) * K + k0 + cg * 8, &la[t * 8]);
    gload_lds16(Bw + (size_t)(n0 + row) * K + k0 + cg * 8, &lb[t * 8]);
  };

  stage(0);
  if (nt > 1) stage(1);
  if (nt > 2) stage(2);

  const unsigned base0 = lds_off(lds);
  unsigned offA[4], offB[2];
#pragma unroll
  for (int m = 0; m < 4; ++m) {
    int r = wm * 64 + m * 16 + ln;
    int Ln = r >> 1, p = ((r & 1) * 4 + lg) ^ (Ln & 7);
    offA[m] = (unsigned)((Ln * 64 + p * 8) * 2);
  }
#pragma unroll
  for (int n = 0; n < 2; ++n) {
    int r = wn * 32 + n * 16 + ln;
    int Ln = r >> 1, p = ((r & 1) * 4 + lg) ^ (Ln & 7);
    offB[n] = (unsigned)(8192 + (Ln * 64 + p * 8) * 2);
  }

  f32x4 acc[4][2] = {};

  for (int tile = 0; tile < nt; ++tile) {
    const int rem = nt - 1 - tile;
    if (rem >= 2)      { asm volatile("s_waitcnt vmcnt(4)"); }
    else if (rem == 1) { asm volatile("s_waitcnt vmcnt(2)"); }
    else               { asm volatile("s_waitcnt vmcnt(0)"); }
    __builtin_amdgcn_sched_barrier(0);
    __builtin_amdgcn_s_barrier();
    const unsigned bb = base0 + (unsigned)((tile & 3) * (BUFU * 2));
    bf16x8 af[4], bf[2];
#pragma unroll
    for (int m = 0; m < 4; ++m) af[m] = ds_read16(bb + offA[m]);
#pragma unroll
    for (int n = 0; n < 2; ++n) bf[n] = ds_read16(bb + offB[n]);
    if (tile + 3 < nt) stage(tile + 3);
    asm volatile("s_waitcnt lgkmcnt(0)");
    __builtin_amdgcn_sched_barrier(0);
    __builtin_amdgcn_s_setprio(1);
#pragma unroll
    for (int m = 0; m < 4; ++m)
#pragma unroll
      for (int n = 0; n < 2; ++n)
        acc[m][n] = __builtin_amdgcn_mfma_f32_16x16x32_bf16(af[m], bf[n], acc[m][n], 0, 0, 0);
    __builtin_amdgcn_s_setprio(0);
  }

  const int rbase = m0 + wm * 64 + lg * 4;
  const int cbase = n0 + wn * 32 + ln;
#pragma unroll
  for (int m = 0; m < 4; ++m) {
#pragma unroll
    for (int n = 0; n < 2; ++n) {
      int col = cbase + n * 16;
#pragma unroll
      for (int j = 0; j < 4; ++j) {
        int row = rbase + m * 16 + j;
        outF[(size_t)row * N + col] = acc[m][n][j] + resid[(size_t)row * N + col];
      }
    }
  }
}

__global__ __launch_bounds__(512, 4) void wo_gemm(
    const unsigned short* __restrict__ A, const unsigned short* __restrict__ Bw,
    int M, int N, int K, const float* __restrict__ resid, float* __restrict__ outF) {
  gemm128_body(A, Bw, M, N, K, resid, outF);
}
__global__ __launch_bounds__(512, 4) void ffn2_gemm(
    const unsigned short* __restrict__ A, const unsigned short* __restrict__ Bw,
    int M, int N, int K, const float* __restrict__ resid, float* __restrict__ outF) {
  gemm128_body(A, Bw, M, N, K, resid, outF);
}

// ---------------- Flash attention: KVBLK=128, paired q-tiles, pipelined DS --
#define PV_ISSUE(c, pa, v0, v1, v2, v3) do {                                   \
  unsigned cg_ = (unsigned)(((((c) * 4) + lg) ^ ln) & 15);                     \
  pa = ds_read16(pbase + (unsigned)(ln * 256) + cg_ * 16);                     \
  v0 = ds_read16(vb + (unsigned)((0 * 16 + ln) * 256) + cg_ * 16);             \
  v1 = ds_read16(vb + (unsigned)((1 * 16 + ln) * 256) + cg_ * 16);             \
  v2 = ds_read16(vb + (unsigned)((2 * 16 + ln) * 256) + cg_ * 16);             \
  v3 = ds_read16(vb + (unsigned)((3 * 16 + ln) * 256) + cg_ * 16);             \
} while (0)

#define PV_MFMA(pa, v0, v1, v2, v3) do {                                       \
  oacc[0] = __builtin_amdgcn_mfma_f32_16x16x32_bf16(pa, v0, oacc[0], 0, 0, 0); \
  oacc[1] = __builtin_amdgcn_mfma_f32_16x16x32_bf16(pa, v1, oacc[1], 0, 0, 0); \
  oacc[2] = __builtin_amdgcn_mfma_f32_16x16x32_bf16(pa, v2, oacc[2], 0, 0, 0); \
  oacc[3] = __builtin_amdgcn_mfma_f32_16x16x32_bf16(pa, v3, oacc[3], 0, 0, 0); \
} while (0)

__global__ __launch_bounds__(256, 2) void attn_kernel(
    const unsigned short* __restrict__ qg, const unsigned short* __restrict__ kg,
    const unsigned short* __restrict__ vt, unsigned short* __restrict__ og) {
  __shared__ __attribute__((aligned(16))) unsigned short Kl[2][8192];
  __shared__ __attribute__((aligned(16))) unsigned short Vl[2][8192];
  __shared__ __attribute__((aligned(16))) unsigned short Pl[4][2048];
  const int t = threadIdx.x, lane = t & 63, w = t >> 6;
  const int lg = lane >> 4, ln = lane & 15;

  int bid = blockIdx.x;
  int nl = (bid & 7) * 64 + (bid >> 3);
  int bh = nl >> 4, pi = nl & 15;
  int b = bh >> 4, h = bh & 15;

  const unsigned kbase = lds_off(&Kl[0][0]);
  const unsigned vbase = lds_off(&Vl[0][0]);
  const unsigned pbase = lds_off(&Pl[w][0]);

  auto runq = [&](int qtile, bool first) {
    const int q0 = qtile * 64;
    const int qw = q0 + w * 16;
    const int nt = (q0 >> 7) + 1;

    bf16x8 aq[2];
    {
      const unsigned short* qp =
          qg + (size_t)(b * S_ + qw + ln) * D_ + h * DK_ + lg * 8;
      aq[0] = *reinterpret_cast<const bf16x8*>(qp);
      aq[1] = *reinterpret_cast<const bf16x8*>(qp + 32);
    }
    asm volatile("" : : "v"(aq[0]), "v"(aq[1]));

    float mr = -1e30f, lr = 0.f;
    f32x4 oacc[4] = {};

    auto stage = [&](int kt) {
      const int buf = kt & 1;
      const int kv0 = kt * 128;
#pragma unroll
      for (int i = 0; i < 4; ++i) {
        int g = i * 256 + t;
        int row = g >> 3, cg = g & 7, sg = cg ^ (row & 7);
        gload_lds16(kg + (size_t)(b * S_ + kv0 + row) * D_ + h * DK_ + sg * 8,
                    &Kl[buf][g * 8]);
      }
#pragma unroll
      for (int i = 0; i < 4; ++i) {
        int g = i * 256 + t;
        int row = g >> 4, cg = g & 15, sg = cg ^ (row & 15);
        gload_lds16(vt + (size_t)(b * D_ + h * DK_ + row) * S_ + kv0 + sg * 8,
                    &Vl[buf][g * 8]);
      }
    };

    if (!first) __builtin_amdgcn_s_barrier();
    stage(0);

    auto ctile = [&](int kt, bool dm) {
      const unsigned kb = kbase + (unsigned)((kt & 1) * 16384);
      const unsigned vb = vbase + (unsigned)((kt & 1) * 16384);
      f32x4 sc[8] = {};
      bf16x8 kf[8], kf2[8];
#pragma unroll
      for (int n = 0; n < 8; ++n) {
        int r = n * 16 + ln;
        int cg0 = lg ^ (r & 7);
        kf[n] = ds_read16(kb + (unsigned)((r * 128 + cg0 * 16)));
      }
#pragma unroll
      for (int n = 0; n < 8; ++n) {
        int r = n * 16 + ln;
        int cg1 = (4 + lg) ^ (r & 7);
        kf2[n] = ds_read16(kb + (unsigned)((r * 128 + cg1 * 16)));
      }
      if (!dm) stage(kt + 1);
      asm volatile("s_waitcnt lgkmcnt(8)");
      __builtin_amdgcn_sched_barrier(0);
#pragma unroll
      for (int n = 0; n < 8; ++n)
        sc[n] = __builtin_amdgcn_mfma_f32_16x16x32_bf16(kf[n], aq[0], sc[n], 0, 0, 0);
      asm volatile("s_waitcnt lgkmcnt(0)");
      __builtin_amdgcn_sched_barrier(0);
#pragma unroll
      for (int n = 0; n < 8; ++n)
        sc[n] = __builtin_amdgcn_mfma_f32_16x16x32_bf16(kf2[n], aq[1], sc[n], 0, 0, 0);
      if (dm) {
        const int kv0 = kt * 128;
        const int qi = qw + ln;
#pragma unroll
        for (int n = 0; n < 8; ++n)
#pragma unroll
          for (int j = 0; j < 4; ++j)
            if ((kv0 + n * 16 + lg * 4 + j) > qi) sc[n][j] = -1e30f;
      }
      float mx = -1e30f;
#pragma unroll
      for (int n = 0; n < 8; ++n) {
        float a = fmaxf(fmaxf(sc[n][0], sc[n][1]), fmaxf(sc[n][2], sc[n][3]));
        mx = fmaxf(mx, a);
      }
      mx = fmaxf(mx, __shfl_xor(mx, 16));
      mx = fmaxf(mx, __shfl_xor(mx, 32));
      float mn = fmaxf(mr, mx);
      float ps = 0.f;
#pragma unroll
      for (int n = 0; n < 8; ++n)
#pragma unroll
        for (int j = 0; j < 4; ++j) {
          float p = fexp2(sc[n][j] - mn);
          sc[n][j] = p;
          ps += p;
        }
      if (__all(mx <= mr)) {
        lr += ps;
      } else {
        float sf = fexp2(mr - mn);
        mr = mn;
        lr = lr * sf + ps;
#pragma unroll
        for (int j = 0; j < 4; ++j) {
          float sfj = __shfl(sf, lg * 4 + j);
#pragma unroll
          for (int f = 0; f < 4; ++f) oacc[f][j] *= sfj;
        }
      }
#pragma unroll
      for (int n = 0; n < 8; ++n) {
        int kvc = n * 16 + lg * 4;
        int gsw = ((kvc >> 3) ^ ln) & 15;
        unsigned pa_addr = pbase + (unsigned)(ln * 256 + gsw * 16 + (kvc & 7) * 2);
        ds_write32(pa_addr, cvt_pk_bf16(sc[n][0], sc[n][1]));
        ds_write32(pa_addr + 4, cvt_pk_bf16(sc[n][2], sc[n][3]));
      }
      asm volatile("s_waitcnt lgkmcnt(0)");
      __builtin_amdgcn_sched_barrier(0);
      bf16x8 paA, vA0, vA1, vA2, vA3, paB, vB0, vB1, vB2, vB3;
      PV_ISSUE(0, paA, vA0, vA1, vA2, vA3);
      PV_ISSUE(1, paB, vB0, vB1, vB2, vB3);
      asm volatile("s_waitcnt lgkmcnt(5)");
      __builtin_amdgcn_sched_barrier(0);
      PV_MFMA(paA, vA0, vA1, vA2, vA3);
      PV_ISSUE(2, paA, vA0, vA1, vA2, vA3);
      asm volatile("s_waitcnt lgkmcnt(5)");
      __builtin_amdgcn_sched_barrier(0);
      PV_MFMA(paB, vB0, vB1, vB2, vB3);
      PV_ISSUE(3, paB, vB0, vB1, vB2, vB3);
      asm volatile("s_waitcnt lgkmcnt(5)");
      __builtin_amdgcn_sched_barrier(0);
      PV_MFMA(paA, vA0, vA1, vA2, vA3);
      asm volatile("s_waitcnt lgkmcnt(0)");
      __builtin_amdgcn_sched_barrier(0);
      PV_MFMA(paB, vB0, vB1, vB2, vB3);
    };

    for (int kt = 0; kt < nt - 1; ++kt) {
      asm volatile("s_waitcnt vmcnt(0)");
      __builtin_amdgcn_sched_barrier(0);
      __builtin_amdgcn_s_barrier();
      ctile(kt, false);
    }
    asm volatile("s_waitcnt vmcnt(0)");
    __builtin_amdgcn_sched_barrier(0);
    __builtin_amdgcn_s_barrier();
    ctile(nt - 1, true);

    lr += __shfl_xor(lr, 16);
    lr += __shfl_xor(lr, 32);
#pragma unroll
    for (int j = 0; j < 4; ++j) {
      float lj = __shfl(lr, lg * 4 + j);
      float inv = 1.0f / lj;
      int row = b * S_ + qw + lg * 4 + j;
#pragma unroll
      for (int f = 0; f < 4; ++f)
        og[(size_t)row * D_ + h * DK_ + f * 16 + ln] = bf16r(oacc[f][j] * inv);
    }
  };

  runq(31 - pi, true);
  runq(pi, false);
}

// ---------------- launch ----------------
extern "C" void kernel_launch(void* const* d_in, const int* in_sizes, int n_in,
                              void* d_out, int out_size, void* d_ws, size_t ws_size,
                              hipStream_t stream) {
  const float* x  = (const float*)d_in[0];
  const float* wq = (const float*)d_in[1];
  const float* wk = (const float*)d_in[2];
  const float* wv = (const float*)d_in[3];
  const float* wo = (const float*)d_in[4];
  const float* w1 = (const float*)d_in[5];
  const float* w2 = (const float*)d_in[6];
  const float* g1 = (const float*)d_in[7];
  const float* g2 = (const float*)d_in[8];
  float* out = (float*)d_out;

  char* ws = (char*)d_ws;
  const size_t MB = 1024 * 1024;
  unsigned short* wqkv_b = (unsigned short*)(ws + 0 * MB);   // [3072][1024]
  unsigned short* wo_b   = (unsigned short*)(ws + 6 * MB);
  unsigned short* w1_b   = (unsigned short*)(ws + 8 * MB);
  unsigned short* w2_b   = (unsigned short*)(ws + 16 * MB);
  unsigned short* h_b    = (unsigned short*)(ws + 24 * MB);
  unsigned short* q_b    = (unsigned short*)(ws + 32 * MB);
  unsigned short* k_b    = (unsigned short*)(ws + 40 * MB);
  unsigned short* vt_b   = (unsigned short*)(ws + 48 * MB);
  unsigned short* o_b    = (unsigned short*)(ws + 56 * MB);
  float*          x1     = (float*)(ws + 64 * MB);
  unsigned short* mid    = (unsigned short*)(ws + 80 * MB);

  CvtArgs ca;
  ca.src[0] = wq; ca.dst[0] = wqkv_b;
  ca.src[1] = wk; ca.dst[1] = wqkv_b + (size_t)D_ * D_;
  ca.src[2] = wv; ca.dst[2] = wqkv_b + (size_t)2 * D_ * D_;
  ca.src[3] = wo; ca.dst[3] = wo_b;
  ca.src[4] = w1; ca.dst[4] = w1_b;
  ca.src[5] = w2; ca.dst[5] = w2_b;
  int q4 = D_ * D_ / 4, f4 = F_ * D_ / 4;
  ca.start[0] = 0;
  ca.start[1] = q4;
  ca.start[2] = 2 * q4;
  ca.start[3] = 3 * q4;
  ca.start[4] = 4 * q4;
  ca.start[5] = 4 * q4 + f4;
  ca.start[6] = 4 * q4 + 2 * f4;
  cvt_all_kernel<<<(ca.start[6] + 255) / 256, 256, 0, stream>>>(ca);

  rmsnorm_kernel<<<NTOK, 256, 0, stream>>>(x, g1, h_b);

  // fused QKV: N=3072, paired-K 128^2 / 256 thr, grid 24x32 (768 blocks)
  qkv_gemm<<<dim3(3 * D_ / 128, NTOK / 128), dim3(256), 0, stream>>>(
      h_b, wqkv_b, NTOK, 3 * D_, D_, q_b, k_b, vt_b);

  attn_kernel<<<dim3(512), dim3(256), 0, stream>>>(q_b, k_b, vt_b, o_b);

  // WO + residual: N=1024, 128^2 / 512 thr 4-deep, grid 8x32
  wo_gemm<<<dim3(D_ / 128, NTOK / 128), dim3(512), 0, stream>>>(
      o_b, wo_b, NTOK, D_, D_, x, x1);

  rmsnorm_kernel<<<NTOK, 256, 0, stream>>>(x1, g2, h_b);

  // FFN1 + fast GELU: N=4096, 256^2 BK=64 8-phase, grid 16x16 (256 blocks)
  ffn1_gemm<<<dim3(F_ / 256, NTOK / 256), dim3(512), 0, stream>>>(
      h_b, w1_b, NTOK, F_, D_, mid);

  // FFN2 + residual: N=1024, 128^2 / 512 thr 4-deep, grid 8x32
  ffn2_gemm<<<dim3(D_ / 128, NTOK / 128), dim3(512), 0, stream>>>(
      mid, w2_b, NTOK, D_, F_, x1, out);
}

// Round 21
// 201.108 us; speedup vs baseline: 1.0613x; 1.0079x over previous
//
#include <hip/hip_runtime.h>
#include <hip/hip_bf16.h>
#include <math.h>

#define B_   2
#define S_   2048
#define D_   1024
#define H_   16
#define DK_  64
#define F_   4096
#define NTOK (B_ * S_)

typedef __bf16 bf16x8 __attribute__((ext_vector_type(8)));
typedef float  f32x4  __attribute__((ext_vector_type(4)));

__device__ __forceinline__ unsigned short bf16r(float f) {
  unsigned u = __builtin_bit_cast(unsigned, f);
  u += 0x7fffu + ((u >> 16) & 1u);
  return (unsigned short)(u >> 16);
}

__device__ __forceinline__ void gload_lds16(const void* g, void* l) {
  __builtin_amdgcn_global_load_lds(
      (__attribute__((address_space(1))) void*)g,
      (__attribute__((address_space(3))) void*)l, 16, 0, 0);
}

__device__ __forceinline__ unsigned lds_off(void* p) {
  return (unsigned)(size_t)(__attribute__((address_space(3))) void*)p;
}
__device__ __forceinline__ bf16x8 ds_read16(unsigned a) {
  bf16x8 r;
  asm volatile("ds_read_b128 %0, %1" : "=v"(r) : "v"(a));
  return r;
}
__device__ __forceinline__ void ds_write32(unsigned a, unsigned v) {
  asm volatile("ds_write_b32 %0, %1" : : "v"(a), "v"(v));
}
__device__ __forceinline__ void ds_write16b(unsigned a, unsigned v) {
  asm volatile("ds_write_b16 %0, %1" : : "v"(a), "v"(v));
}
__device__ __forceinline__ float fexp2(float x) {
  float r;
  asm volatile("v_exp_f32 %0, %1\n\ts_nop 0" : "=v"(r) : "v"(x));
  return r;
}
__device__ __forceinline__ unsigned cvt_pk_bf16(float lo, float hi) {
  unsigned r;
  asm volatile("v_cvt_pk_bf16_f32 %0, %1, %2" : "=v"(r) : "v"(lo), "v"(hi));
  return r;
}

__device__ __forceinline__ float gelu_fast(float x) {
  float y = 0.7978845608f * x * (1.0f + 0.044715f * x * x);
  float e = fexp2(2.885390082f * y);
  float t = 1.0f - 2.0f / (e + 1.0f);
  return 0.5f * x * (1.0f + t);
}

#define QSCL 0.18033688f  /* (1/8) * log2(e), folded into Q at QKV epilogue */

// ---------------- fused prep: rmsnorm1 (blocks 0..NTOK-1) + weight cvt ------
struct PrepArgs {
  const float* src[6];
  unsigned short* dst[6];
  int start[7];
  const float* x;
  const float* g1;
  unsigned short* h;
};
__global__ __launch_bounds__(256) void prep_kernel(PrepArgs a) {
  if ((int)blockIdx.x < NTOK) {
    // rmsnorm row
    int row = blockIdx.x;
    int t = threadIdx.x, lane = t & 63, w = t >> 6;
    float4 v = reinterpret_cast<const float4*>(a.x + (size_t)row * D_)[t];
    float ss = v.x * v.x + v.y * v.y + v.z * v.z + v.w * v.w;
#pragma unroll
    for (int d = 1; d < 64; d <<= 1) ss += __shfl_xor(ss, d);
    __shared__ float red[4];
    if (lane == 0) red[w] = ss;
    __syncthreads();
    float tot = red[0] + red[1] + red[2] + red[3];
    float rstd = rsqrtf(tot * (1.0f / D_) + 1e-5f);
    float4 gv = reinterpret_cast<const float4*>(a.g1)[t];
    ushort4 o;
    o.x = bf16r(v.x * rstd * gv.x);
    o.y = bf16r(v.y * rstd * gv.y);
    o.z = bf16r(v.z * rstd * gv.z);
    o.w = bf16r(v.w * rstd * gv.w);
    reinterpret_cast<ushort4*>(a.h + (size_t)row * D_)[t] = o;
  } else {
    // weight fp32 -> bf16 (float4 chunk)
    int i = ((int)blockIdx.x - NTOK) * 256 + (int)threadIdx.x;
    if (i >= a.start[6]) return;
    int k = 0;
#pragma unroll
    for (int j = 1; j < 6; ++j)
      if (i >= a.start[j]) k = j;
    int off = i - a.start[k];
    float4 v = reinterpret_cast<const float4*>(a.src[k])[off];
    ushort4 o;
    o.x = bf16r(v.x); o.y = bf16r(v.y); o.z = bf16r(v.z); o.w = bf16r(v.w);
    reinterpret_cast<ushort4*>(a.dst[k])[off] = o;
  }
}

// ---------------- RMSNorm (fp32 in, bf16 out) ----------------
__global__ __launch_bounds__(256) void rmsnorm_kernel(
    const float* __restrict__ x, const float* __restrict__ g,
    unsigned short* __restrict__ out) {
  int row = blockIdx.x;
  int t = threadIdx.x, lane = t & 63, w = t >> 6;
  float4 v = reinterpret_cast<const float4*>(x + (size_t)row * D_)[t];
  float ss = v.x * v.x + v.y * v.y + v.z * v.z + v.w * v.w;
#pragma unroll
  for (int d = 1; d < 64; d <<= 1) ss += __shfl_xor(ss, d);
  __shared__ float red[4];
  if (lane == 0) red[w] = ss;
  __syncthreads();
  float tot = red[0] + red[1] + red[2] + red[3];
  float rstd = rsqrtf(tot * (1.0f / D_) + 1e-5f);
  float4 gv = reinterpret_cast<const float4*>(g)[t];
  ushort4 o;
  o.x = bf16r(v.x * rstd * gv.x);
  o.y = bf16r(v.y * rstd * gv.y);
  o.z = bf16r(v.z * rstd * gv.z);
  o.w = bf16r(v.w * rstd * gv.w);
  reinterpret_cast<ushort4*>(out + (size_t)row * D_)[t] = o;
}

// wave-tile (64x64) LDS-staged coalesced bf16 store (proven round 15)
__device__ __forceinline__ void store_tile_coalesced(
    const f32x4 (&acc)[4][4], unsigned ew, int lane, int lg, int ln,
    unsigned short* __restrict__ dst, size_t stride, int rowbase, int colbase,
    bool gelu, float scl) {
#pragma unroll
  for (int m = 0; m < 4; ++m)
#pragma unroll
    for (int n = 0; n < 4; ++n)
#pragma unroll
      for (int j = 0; j < 4; ++j) {
        int lrow = lg * 4 + m * 16 + j;
        int lcol = n * 16 + ln;
        int g = (lcol >> 3) ^ (lrow & 7);
        float v = acc[m][n][j];
        if (gelu) v = gelu_fast(v);
        ds_write16b(ew + (unsigned)((lrow * 64 + g * 8 + (lcol & 7)) * 2),
                    (unsigned)bf16r(v * scl));
      }
  asm volatile("s_waitcnt lgkmcnt(0)");
  __builtin_amdgcn_sched_barrier(0);
  bf16x8 cv[8];
#pragma unroll
  for (int i = 0; i < 8; ++i) {
    int lrow = i * 8 + (lane >> 3);
    int g = (lane & 7) ^ (lrow & 7);
    cv[i] = ds_read16(ew + (unsigned)((lrow * 64 + g * 8) * 2));
  }
  asm volatile("s_waitcnt lgkmcnt(0)");
  __builtin_amdgcn_sched_barrier(0);
#pragma unroll
  for (int i = 0; i < 8; ++i) {
    int lrow = i * 8 + (lane >> 3);
    *reinterpret_cast<bf16x8*>(
        &dst[(size_t)(rowbase + lrow) * stride + colbase + (lane & 7) * 8]) = cv[i];
  }
}

// ======== ffn1: 256x256 / BK=64 / 8-wave / 2-buf 8-phase schedule (m201) ====
__global__ __launch_bounds__(512, 2) void ffn1_gemm(
    const unsigned short* __restrict__ A, const unsigned short* __restrict__ Bw,
    int M, int N, int K, unsigned short* __restrict__ outB) {
  __shared__ __attribute__((aligned(16))) unsigned short lds[65536];  // 128 KB
  const int t = threadIdx.x, lane = t & 63, w = t >> 6;
  const int wm = w >> 2, wn = w & 3;
  const int lg = lane >> 4, ln = lane & 15;

  const int gx = gridDim.x;  // 16
  int bid = blockIdx.y * gx + blockIdx.x;
  int xcd = bid & 7, c = bid >> 3;
  int RX = gx >> 2, RY = gridDim.y >> 1;
  int bx = (xcd & 3) * RX + (c % RX);
  int by = (xcd >> 2) * RY + (c / RX);
  const int m0 = by * 256, n0 = bx * 256;

  const int nt = K >> 6;      // 16 K-tiles of 64
  const int niter = nt >> 1;  // 8

  auto SA = [&](int tile, int h) {
    unsigned short* dst = &lds[(tile & 1) * 32768 + h * 8192];
    const int k0 = tile << 6;
    const int rb = m0 + h * 128;
#pragma unroll
    for (int i = 0; i < 2; ++i) {
      int g = i * 512 + t;
      int row = g >> 3, sg = (g & 7) ^ (row & 7);
      gload_lds16(A + (size_t)(rb + row) * K + k0 + sg * 8, &dst[g * 8]);
    }
  };
  auto SB = [&](int tile, int h) {
    unsigned short* dst = &lds[(tile & 1) * 32768 + 16384 + h * 8192];
    const int k0 = tile << 6;
    const int rb = n0 + h * 128;
#pragma unroll
    for (int i = 0; i < 2; ++i) {
      int g = i * 512 + t;
      int row = g >> 3, sg = (g & 7) ^ (row & 7);
      gload_lds16(Bw + (size_t)(rb + row) * K + k0 + sg * 8, &dst[g * 8]);
    }
  };

  SA(0, 0); SA(0, 1); SB(0, 0); SB(0, 1); SB(1, 0); SB(1, 1);

  const unsigned base0 = lds_off(lds);
  unsigned offA[8], offB[4];
#pragma unroll
  for (int m = 0; m < 8; ++m) {
    int r = wm * 128 + m * 16 + ln;
    offA[m] = (unsigned)(r * 128 + (lg ^ (r & 7)) * 16);
  }
#pragma unroll
  for (int n = 0; n < 4; ++n) {
    int r = wn * 64 + n * 16 + ln;
    offB[n] = (unsigned)(32768 + r * 128 + (lg ^ (r & 7)) * 16);
  }

  f32x4 acc[8][4] = {};

  asm volatile("s_waitcnt vmcnt(0)");
  __builtin_amdgcn_sched_barrier(0);
  __builtin_amdgcn_s_barrier();

  for (int it = 0; it < niter; ++it) {
    const int t0 = 2 * it, t1 = 2 * it + 1;
    const bool more = (it + 1 < niter);
    const unsigned bb0 = base0 + (unsigned)((t0 & 1) * 65536);
    const unsigned bb1 = base0 + (unsigned)((t1 & 1) * 65536);
    bf16x8 bfr[4][2];
#pragma unroll
    for (int q = 0; q < 4; ++q) {
      bf16x8 af[2][2];
      if (q == 0) {
#pragma unroll
        for (int n = 0; n < 4; ++n) {
          bfr[n][0] = ds_read16(bb0 + offB[n]);
          bfr[n][1] = ds_read16(bb0 + (offB[n] ^ 0x40u));
        }
      }
#pragma unroll
      for (int mm = 0; mm < 2; ++mm) {
        af[mm][0] = ds_read16(bb0 + offA[2 * q + mm]);
        af[mm][1] = ds_read16(bb0 + (offA[2 * q + mm] ^ 0x40u));
      }
      if (q == 0)       SA(t1, 0);
      else if (q == 1)  SA(t1, 1);
      else if (q == 2)  { if (more) SB(t0 + 2, 0); }
      else              { if (more) SB(t0 + 2, 1); }
      if (q == 3) {
        if (more) { asm volatile("s_waitcnt vmcnt(4)"); }
        else      { asm volatile("s_waitcnt vmcnt(0)"); }
        __builtin_amdgcn_sched_barrier(0);
      }
      __builtin_amdgcn_s_barrier();
      asm volatile("s_waitcnt lgkmcnt(0)");
      __builtin_amdgcn_sched_barrier(0);
      __builtin_amdgcn_s_setprio(1);
#pragma unroll
      for (int mm = 0; mm < 2; ++mm)
#pragma unroll
        for (int n = 0; n < 4; ++n) {
          acc[2 * q + mm][n] = __builtin_amdgcn_mfma_f32_16x16x32_bf16(
              af[mm][0], bfr[n][0], acc[2 * q + mm][n], 0, 0, 0);
          acc[2 * q + mm][n] = __builtin_amdgcn_mfma_f32_16x16x32_bf16(
              af[mm][1], bfr[n][1], acc[2 * q + mm][n], 0, 0, 0);
        }
      __builtin_amdgcn_s_setprio(0);
      __builtin_amdgcn_s_barrier();
    }
#pragma unroll
    for (int q = 0; q < 4; ++q) {
      bf16x8 af[2][2];
      if (q == 0) {
#pragma unroll
        for (int n = 0; n < 4; ++n) {
          bfr[n][0] = ds_read16(bb1 + offB[n]);
          bfr[n][1] = ds_read16(bb1 + (offB[n] ^ 0x40u));
        }
      }
#pragma unroll
      for (int mm = 0; mm < 2; ++mm) {
        af[mm][0] = ds_read16(bb1 + offA[2 * q + mm]);
        af[mm][1] = ds_read16(bb1 + (offA[2 * q + mm] ^ 0x40u));
      }
      if (more) {
        if (q == 0)      SA(t0 + 2, 0);
        else if (q == 1) SA(t0 + 2, 1);
        else if (q == 2) SB(t1 + 2, 0);
        else             SB(t1 + 2, 1);
      }
      if (q == 3) {
        if (more) { asm volatile("s_waitcnt vmcnt(4)"); }
        else      { asm volatile("s_waitcnt vmcnt(0)"); }
        __builtin_amdgcn_sched_barrier(0);
      }
      __builtin_amdgcn_s_barrier();
      asm volatile("s_waitcnt lgkmcnt(0)");
      __builtin_amdgcn_sched_barrier(0);
      __builtin_amdgcn_s_setprio(1);
#pragma unroll
      for (int mm = 0; mm < 2; ++mm)
#pragma unroll
        for (int n = 0; n < 4; ++n) {
          acc[2 * q + mm][n] = __builtin_amdgcn_mfma_f32_16x16x32_bf16(
              af[mm][0], bfr[n][0], acc[2 * q + mm][n], 0, 0, 0);
          acc[2 * q + mm][n] = __builtin_amdgcn_mfma_f32_16x16x32_bf16(
              af[mm][1], bfr[n][1], acc[2 * q + mm][n], 0, 0, 0);
        }
      __builtin_amdgcn_s_setprio(0);
      __builtin_amdgcn_s_barrier();
    }
  }

  const unsigned ew = base0 + (unsigned)(w * 8192);
  store_tile_coalesced(*reinterpret_cast<const f32x4(*)[4][4]>(&acc[0]),
                       ew, lane, lg, ln, outB, (size_t)N,
                       m0 + wm * 128, n0 + wn * 64, true, 1.0f);
  store_tile_coalesced(*reinterpret_cast<const f32x4(*)[4][4]>(&acc[4]),
                       ew, lane, lg, ln, outB, (size_t)N,
                       m0 + wm * 128 + 64, n0 + wn * 64, true, 1.0f);
}

// ======== 128x128 / 256-thr / NBUF=4 PAIRED GEMM (qkv, round-16 winner) =====
__global__ __launch_bounds__(256, 2) void qkv_gemm(
    const unsigned short* __restrict__ A, const unsigned short* __restrict__ Bw,
    int M, int N, int K,
    unsigned short* __restrict__ outB, unsigned short* __restrict__ outB2,
    unsigned short* __restrict__ outB3) {
  constexpr int BUFU = 8192;
  __shared__ __attribute__((aligned(16))) unsigned short lds[4 * BUFU];  // 64 KB
  const int t = threadIdx.x, lane = t & 63, w = t >> 6;
  const int wm = w >> 1, wn = w & 1;
  const int lg = lane >> 4, ln = lane & 15;

  const int gx = gridDim.x;
  int bid = blockIdx.y * gx + blockIdx.x;
  int xcd = bid & 7, c = bid >> 3;
  int RX = gx >> 2, RY = gridDim.y >> 1;
  int bx = (xcd & 3) * RX + (c % RX);
  int by = (xcd >> 2) * RY + (c / RX);
  const int m0 = by * 128, n0 = bx * 128;

  const int nt = K >> 5;  // even

  auto stage = [&](int tile) {
    int buf = tile & 3;
    const int k0 = tile << 5;
    unsigned short* la = &lds[buf * BUFU];
    unsigned short* lb = la + 4096;
#pragma unroll
    for (int i = 0; i < 2; ++i) {
      int g = i * 256 + t;
      int Ln = g >> 3, p = g & 7, u = p ^ (Ln & 7);
      int row = 2 * Ln + (u >> 2), cg = u & 3;
      gload_lds16(A + (size_t)(m0 + row) * K + k0 + cg * 8, &la[g * 8]);
    }
#pragma unroll
    for (int i = 0; i < 2; ++i) {
      int g = i * 256 + t;
      int Ln = g >> 3, p = g & 7, u = p ^ (Ln & 7);
      int row = 2 * Ln + (u >> 2), cg = u & 3;
      gload_lds16(Bw + (size_t)(n0 + row) * K + k0 + cg * 8, &lb[g * 8]);
    }
  };

  stage(0);
  stage(1);

  const unsigned base0 = lds_off(lds);
  unsigned offA[4], offB[4];
#pragma unroll
  for (int m = 0; m < 4; ++m) {
    int r = wm * 64 + m * 16 + ln;
    int Ln = r >> 1, p = ((r & 1) * 4 + lg) ^ (Ln & 7);
    offA[m] = (unsigned)((Ln * 64 + p * 8) * 2);
  }
#pragma unroll
  for (int n = 0; n < 4; ++n) {
    int r = wn * 64 + n * 16 + ln;
    int Ln = r >> 1, p = ((r & 1) * 4 + lg) ^ (Ln & 7);
    offB[n] = (unsigned)(8192 + (Ln * 64 + p * 8) * 2);
  }

  f32x4 acc[4][4] = {};

  for (int tp = 0; tp < nt; tp += 2) {
    asm volatile("s_waitcnt vmcnt(0)");
    __builtin_amdgcn_sched_barrier(0);
    __builtin_amdgcn_s_barrier();
    const unsigned bb0 = base0 + (unsigned)((tp & 3) * (BUFU * 2));
    const unsigned bb1 = base0 + (unsigned)(((tp + 1) & 3) * (BUFU * 2));
    bf16x8 af[4], bf[4], af2[4], bf2[4];
#pragma unroll
    for (int m = 0; m < 4; ++m) af[m] = ds_read16(bb0 + offA[m]);
#pragma unroll
    for (int n = 0; n < 4; ++n) bf[n] = ds_read16(bb0 + offB[n]);
#pragma unroll
    for (int m = 0; m < 4; ++m) af2[m] = ds_read16(bb1 + offA[m]);
#pragma unroll
    for (int n = 0; n < 4; ++n) bf2[n] = ds_read16(bb1 + offB[n]);
    if (tp + 2 < nt) stage(tp + 2);
    if (tp + 3 < nt) stage(tp + 3);
    asm volatile("s_waitcnt lgkmcnt(8)");
    __builtin_amdgcn_sched_barrier(0);
    __builtin_amdgcn_s_setprio(1);
#pragma unroll
    for (int m = 0; m < 4; ++m)
#pragma unroll
      for (int n = 0; n < 4; ++n)
        acc[m][n] = __builtin_amdgcn_mfma_f32_16x16x32_bf16(af[m], bf[n], acc[m][n], 0, 0, 0);
    __builtin_amdgcn_s_setprio(0);
    asm volatile("s_waitcnt lgkmcnt(0)");
    __builtin_amdgcn_sched_barrier(0);
    __builtin_amdgcn_s_setprio(1);
#pragma unroll
    for (int m = 0; m < 4; ++m)
#pragma unroll
      for (int n = 0; n < 4; ++n)
        acc[m][n] = __builtin_amdgcn_mfma_f32_16x16x32_bf16(af2[m], bf2[n], acc[m][n], 0, 0, 0);
    __builtin_amdgcn_s_setprio(0);
  }

  __builtin_amdgcn_s_barrier();
  const unsigned ew = base0 + (unsigned)(w * 8192);
  const int col0 = n0 + wn * 64;
  const int rowbase = m0 + wm * 64;
  if (col0 < 2 * D_) {
    const float scl = (col0 < D_) ? QSCL : 1.0f;
    unsigned short* dst = (col0 < D_) ? outB : outB2;
    const int cb = (col0 < D_) ? col0 : col0 - D_;
    store_tile_coalesced(acc, ew, lane, lg, ln, dst, (size_t)D_,
                         rowbase, cb, false, scl);
  } else {
    const int cb = col0 - 2 * D_;
    const int bb2 = rowbase >> 11;
    const int s0base = rowbase & (S_ - 1);
#pragma unroll
    for (int m = 0; m < 4; ++m) {
#pragma unroll
      for (int n = 0; n < 4; ++n) {
        int col = cb + n * 16 + ln;
        ushort4 pk;
        pk.x = bf16r(acc[m][n][0]);
        pk.y = bf16r(acc[m][n][1]);
        pk.z = bf16r(acc[m][n][2]);
        pk.w = bf16r(acc[m][n][3]);
        *reinterpret_cast<ushort4*>(
            &outB3[((size_t)(bb2 * D_) + col) * S_ + s0base + lg * 4 + m * 16]) = pk;
      }
    }
  }
}

// ======== 128x128 4-deep pipelined GEMM (N=1024 outputs, +resid->fp32) ======
// Round-18 proven: counted vmcnt(4)/(2) NEVER drains to 0 in steady state.
__device__ __forceinline__ void gemm128_body(
    const unsigned short* __restrict__ A, const unsigned short* __restrict__ Bw,
    int M, int N, int K,
    const float* __restrict__ resid, float* __restrict__ outF) {
  constexpr int BUFU = 256 * 32;
  __shared__ __attribute__((aligned(16))) unsigned short lds[4 * BUFU];
  const int t = threadIdx.x, lane = t & 63, w = t >> 6;
  const int wm = w >> 2, wn = w & 3;
  const int lg = lane >> 4, ln = lane & 15;

  const int gx = gridDim.x;
  int bid = blockIdx.y * gx + blockIdx.x;
  int RX = gx >> 2, RY = gridDim.y >> 1;
  int xcd = bid & 7, c = bid >> 3;
  int bx = (xcd & 3) * RX + (c % RX);
  int by = (xcd >> 2) * RY + (c / RX);
  const int m0 = by * 128, n0 = bx * 128;

  const int nt = K >> 5;

  auto stage = [&](int tile) {
    const int buf = tile & 3;
    const int k0 = tile << 5;
    unsigned short* la = &lds[buf * BUFU];
    unsigned short* lb = la + 4096;
    int Ln = t >> 3, p = t & 7, u = p ^ (Ln & 7);
    int row = 2 * Ln + (u >> 2), cg = u & 3;
    gload_lds16(A + (size_t)(m0 + row) * K + k0 + cg * 8, &la[t * 8]);
    gload_lds16(Bw + (size_t)(n0 + row) * K + k0 + cg * 8, &lb[t * 8]);
  };

  stage(0);
  if (nt > 1) stage(1);
  if (nt > 2) stage(2);

  const unsigned base0 = lds_off(lds);
  unsigned offA[4], offB[2];
#pragma unroll
  for (int m = 0; m < 4; ++m) {
    int r = wm * 64 + m * 16 + ln;
    int Ln = r >> 1, p = ((r & 1) * 4 + lg) ^ (Ln & 7);
    offA[m] = (unsigned)((Ln * 64 + p * 8) * 2);
  }
#pragma unroll
  for (int n = 0; n < 2; ++n) {
    int r = wn * 32 + n * 16 + ln;
    int Ln = r >> 1, p = ((r & 1) * 4 + lg) ^ (Ln & 7);
    offB[n] = (unsigned)(8192 + (Ln * 64 + p * 8) * 2);
  }

  f32x4 acc[4][2] = {};

  for (int tile = 0; tile < nt; ++tile) {
    const int rem = nt - 1 - tile;
    if (rem >= 2)      { asm volatile("s_waitcnt vmcnt(4)"); }
    else if (rem == 1) { asm volatile("s_waitcnt vmcnt(2)"); }
    else               { asm volatile("s_waitcnt vmcnt(0)"); }
    __builtin_amdgcn_sched_barrier(0);
    __builtin_amdgcn_s_barrier();
    const unsigned bb = base0 + (unsigned)((tile & 3) * (BUFU * 2));
    bf16x8 af[4], bf[2];
#pragma unroll
    for (int m = 0; m < 4; ++m) af[m] = ds_read16(bb + offA[m]);
#pragma unroll
    for (int n = 0; n < 2; ++n) bf[n] = ds_read16(bb + offB[n]);
    if (tile + 3 < nt) stage(tile + 3);
    asm volatile("s_waitcnt lgkmcnt(0)");
    __builtin_amdgcn_sched_barrier(0);
    __builtin_amdgcn_s_setprio(1);
#pragma unroll
    for (int m = 0; m < 4; ++m)
#pragma unroll
      for (int n = 0; n < 2; ++n)
        acc[m][n] = __builtin_amdgcn_mfma_f32_16x16x32_bf16(af[m], bf[n], acc[m][n], 0, 0, 0);
    __builtin_amdgcn_s_setprio(0);
  }

  const int rbase = m0 + wm * 64 + lg * 4;
  const int cbase = n0 + wn * 32 + ln;
#pragma unroll
  for (int m = 0; m < 4; ++m) {
#pragma unroll
    for (int n = 0; n < 2; ++n) {
      int col = cbase + n * 16;
#pragma unroll
      for (int j = 0; j < 4; ++j) {
        int row = rbase + m * 16 + j;
        outF[(size_t)row * N + col] = acc[m][n][j] + resid[(size_t)row * N + col];
      }
    }
  }
}

__global__ __launch_bounds__(512, 4) void wo_gemm(
    const unsigned short* __restrict__ A, const unsigned short* __restrict__ Bw,
    int M, int N, int K, const float* __restrict__ resid, float* __restrict__ outF) {
  gemm128_body(A, Bw, M, N, K, resid, outF);
}
__global__ __launch_bounds__(512, 4) void ffn2_gemm(
    const unsigned short* __restrict__ A, const unsigned short* __restrict__ Bw,
    int M, int N, int K, const float* __restrict__ resid, float* __restrict__ outF) {
  gemm128_body(A, Bw, M, N, K, resid, outF);
}

// ---------------- Flash attention: KVBLK=128, paired q-tiles, pipelined DS --
#define PV_ISSUE(c, pa, v0, v1, v2, v3) do {                                   \
  unsigned cg_ = (unsigned)(((((c) * 4) + lg) ^ ln) & 15);                     \
  pa = ds_read16(pbase + (unsigned)(ln * 256) + cg_ * 16);                     \
  v0 = ds_read16(vb + (unsigned)((0 * 16 + ln) * 256) + cg_ * 16);             \
  v1 = ds_read16(vb + (unsigned)((1 * 16 + ln) * 256) + cg_ * 16);             \
  v2 = ds_read16(vb + (unsigned)((2 * 16 + ln) * 256) + cg_ * 16);             \
  v3 = ds_read16(vb + (unsigned)((3 * 16 + ln) * 256) + cg_ * 16);             \
} while (0)

#define PV_MFMA(pa, v0, v1, v2, v3) do {                                       \
  oacc[0] = __builtin_amdgcn_mfma_f32_16x16x32_bf16(pa, v0, oacc[0], 0, 0, 0); \
  oacc[1] = __builtin_amdgcn_mfma_f32_16x16x32_bf16(pa, v1, oacc[1], 0, 0, 0); \
  oacc[2] = __builtin_amdgcn_mfma_f32_16x16x32_bf16(pa, v2, oacc[2], 0, 0, 0); \
  oacc[3] = __builtin_amdgcn_mfma_f32_16x16x32_bf16(pa, v3, oacc[3], 0, 0, 0); \
} while (0)

__global__ __launch_bounds__(256, 2) void attn_kernel(
    const unsigned short* __restrict__ qg, const unsigned short* __restrict__ kg,
    const unsigned short* __restrict__ vt, unsigned short* __restrict__ og) {
  __shared__ __attribute__((aligned(16))) unsigned short Kl[2][8192];
  __shared__ __attribute__((aligned(16))) unsigned short Vl[2][8192];
  __shared__ __attribute__((aligned(16))) unsigned short Pl[4][2048];
  const int t = threadIdx.x, lane = t & 63, w = t >> 6;
  const int lg = lane >> 4, ln = lane & 15;

  int bid = blockIdx.x;
  int nl = (bid & 7) * 64 + (bid >> 3);
  int bh = nl >> 4, pi = nl & 15;
  int b = bh >> 4, h = bh & 15;

  const unsigned kbase = lds_off(&Kl[0][0]);
  const unsigned vbase = lds_off(&Vl[0][0]);
  const unsigned pbase = lds_off(&Pl[w][0]);

  auto runq = [&](int qtile, bool first) {
    const int q0 = qtile * 64;
    const int qw = q0 + w * 16;
    const int nt = (q0 >> 7) + 1;

    bf16x8 aq[2];
    {
      const unsigned short* qp =
          qg + (size_t)(b * S_ + qw + ln) * D_ + h * DK_ + lg * 8;
      aq[0] = *reinterpret_cast<const bf16x8*>(qp);
      aq[1] = *reinterpret_cast<const bf16x8*>(qp + 32);
    }
    asm volatile("" : : "v"(aq[0]), "v"(aq[1]));

    float mr = -1e30f, lr = 0.f;
    f32x4 oacc[4] = {};

    auto stage = [&](int kt) {
      const int buf = kt & 1;
      const int kv0 = kt * 128;
#pragma unroll
      for (int i = 0; i < 4; ++i) {
        int g = i * 256 + t;
        int row = g >> 3, cg = g & 7, sg = cg ^ (row & 7);
        gload_lds16(kg + (size_t)(b * S_ + kv0 + row) * D_ + h * DK_ + sg * 8,
                    &Kl[buf][g * 8]);
      }
#pragma unroll
      for (int i = 0; i < 4; ++i) {
        int g = i * 256 + t;
        int row = g >> 4, cg = g & 15, sg = cg ^ (row & 15);
        gload_lds16(vt + (size_t)(b * D_ + h * DK_ + row) * S_ + kv0 + sg * 8,
                    &Vl[buf][g * 8]);
      }
    };

    if (!first) __builtin_amdgcn_s_barrier();
    stage(0);

    auto ctile = [&](int kt, bool dm) {
      const unsigned kb = kbase + (unsigned)((kt & 1) * 16384);
      const unsigned vb = vbase + (unsigned)((kt & 1) * 16384);
      f32x4 sc[8] = {};
      bf16x8 kf[8], kf2[8];
#pragma unroll
      for (int n = 0; n < 8; ++n) {
        int r = n * 16 + ln;
        int cg0 = lg ^ (r & 7);
        kf[n] = ds_read16(kb + (unsigned)((r * 128 + cg0 * 16)));
      }
#pragma unroll
      for (int n = 0; n < 8; ++n) {
        int r = n * 16 + ln;
        int cg1 = (4 + lg) ^ (r & 7);
        kf2[n] = ds_read16(kb + (unsigned)((r * 128 + cg1 * 16)));
      }
      if (!dm) stage(kt + 1);
      asm volatile("s_waitcnt lgkmcnt(8)");
      __builtin_amdgcn_sched_barrier(0);
#pragma unroll
      for (int n = 0; n < 8; ++n)
        sc[n] = __builtin_amdgcn_mfma_f32_16x16x32_bf16(kf[n], aq[0], sc[n], 0, 0, 0);
      asm volatile("s_waitcnt lgkmcnt(0)");
      __builtin_amdgcn_sched_barrier(0);
#pragma unroll
      for (int n = 0; n < 8; ++n)
        sc[n] = __builtin_amdgcn_mfma_f32_16x16x32_bf16(kf2[n], aq[1], sc[n], 0, 0, 0);
      if (dm) {
        const int kv0 = kt * 128;
        const int qi = qw + ln;
#pragma unroll
        for (int n = 0; n < 8; ++n)
#pragma unroll
          for (int j = 0; j < 4; ++j)
            if ((kv0 + n * 16 + lg * 4 + j) > qi) sc[n][j] = -1e30f;
      }
      float mx = -1e30f;
#pragma unroll
      for (int n = 0; n < 8; ++n) {
        float a = fmaxf(fmaxf(sc[n][0], sc[n][1]), fmaxf(sc[n][2], sc[n][3]));
        mx = fmaxf(mx, a);
      }
      mx = fmaxf(mx, __shfl_xor(mx, 16));
      mx = fmaxf(mx, __shfl_xor(mx, 32));
      float mn = fmaxf(mr, mx);
      float ps = 0.f;
#pragma unroll
      for (int n = 0; n < 8; ++n)
#pragma unroll
        for (int j = 0; j < 4; ++j) {
          float p = fexp2(sc[n][j] - mn);
          sc[n][j] = p;
          ps += p;
        }
      if (__all(mx <= mr)) {
        lr += ps;
      } else {
        float sf = fexp2(mr - mn);
        mr = mn;
        lr = lr * sf + ps;
#pragma unroll
        for (int j = 0; j < 4; ++j) {
          float sfj = __shfl(sf, lg * 4 + j);
#pragma unroll
          for (int f = 0; f < 4; ++f) oacc[f][j] *= sfj;
        }
      }
#pragma unroll
      for (int n = 0; n < 8; ++n) {
        int kvc = n * 16 + lg * 4;
        int gsw = ((kvc >> 3) ^ ln) & 15;
        unsigned pa_addr = pbase + (unsigned)(ln * 256 + gsw * 16 + (kvc & 7) * 2);
        ds_write32(pa_addr, cvt_pk_bf16(sc[n][0], sc[n][1]));
        ds_write32(pa_addr + 4, cvt_pk_bf16(sc[n][2], sc[n][3]));
      }
      asm volatile("s_waitcnt lgkmcnt(0)");
      __builtin_amdgcn_sched_barrier(0);
      bf16x8 paA, vA0, vA1, vA2, vA3, paB, vB0, vB1, vB2, vB3;
      PV_ISSUE(0, paA, vA0, vA1, vA2, vA3);
      PV_ISSUE(1, paB, vB0, vB1, vB2, vB3);
      asm volatile("s_waitcnt lgkmcnt(5)");
      __builtin_amdgcn_sched_barrier(0);
      PV_MFMA(paA, vA0, vA1, vA2, vA3);
      PV_ISSUE(2, paA, vA0, vA1, vA2, vA3);
      asm volatile("s_waitcnt lgkmcnt(5)");
      __builtin_amdgcn_sched_barrier(0);
      PV_MFMA(paB, vB0, vB1, vB2, vB3);
      PV_ISSUE(3, paB, vB0, vB1, vB2, vB3);
      asm volatile("s_waitcnt lgkmcnt(5)");
      __builtin_amdgcn_sched_barrier(0);
      PV_MFMA(paA, vA0, vA1, vA2, vA3);
      asm volatile("s_waitcnt lgkmcnt(0)");
      __builtin_amdgcn_sched_barrier(0);
      PV_MFMA(paB, vB0, vB1, vB2, vB3);
    };

    for (int kt = 0; kt < nt - 1; ++kt) {
      asm volatile("s_waitcnt vmcnt(0)");
      __builtin_amdgcn_sched_barrier(0);
      __builtin_amdgcn_s_barrier();
      ctile(kt, false);
    }
    asm volatile("s_waitcnt vmcnt(0)");
    __builtin_amdgcn_sched_barrier(0);
    __builtin_amdgcn_s_barrier();
    ctile(nt - 1, true);

    lr += __shfl_xor(lr, 16);
    lr += __shfl_xor(lr, 32);
#pragma unroll
    for (int j = 0; j < 4; ++j) {
      float lj = __shfl(lr, lg * 4 + j);
      float inv = 1.0f / lj;
      int row = b * S_ + qw + lg * 4 + j;
#pragma unroll
      for (int f = 0; f < 4; ++f)
        og[(size_t)row * D_ + h * DK_ + f * 16 + ln] = bf16r(oacc[f][j] * inv);
    }
  };

  runq(31 - pi, true);
  runq(pi, false);
}

// ---------------- launch ----------------
extern "C" void kernel_launch(void* const* d_in, const int* in_sizes, int n_in,
                              void* d_out, int out_size, void* d_ws, size_t ws_size,
                              hipStream_t stream) {
  const float* x  = (const float*)d_in[0];
  const float* wq = (const float*)d_in[1];
  const float* wk = (const float*)d_in[2];
  const float* wv = (const float*)d_in[3];
  const float* wo = (const float*)d_in[4];
  const float* w1 = (const float*)d_in[5];
  const float* w2 = (const float*)d_in[6];
  const float* g1 = (const float*)d_in[7];
  const float* g2 = (const float*)d_in[8];
  float* out = (float*)d_out;

  char* ws = (char*)d_ws;
  const size_t MB = 1024 * 1024;
  unsigned short* wqkv_b = (unsigned short*)(ws + 0 * MB);   // [3072][1024]
  unsigned short* wo_b   = (unsigned short*)(ws + 6 * MB);
  unsigned short* w1_b   = (unsigned short*)(ws + 8 * MB);
  unsigned short* w2_b   = (unsigned short*)(ws + 16 * MB);
  unsigned short* h_b    = (unsigned short*)(ws + 24 * MB);
  unsigned short* q_b    = (unsigned short*)(ws + 32 * MB);
  unsigned short* k_b    = (unsigned short*)(ws + 40 * MB);
  unsigned short* vt_b   = (unsigned short*)(ws + 48 * MB);
  unsigned short* o_b    = (unsigned short*)(ws + 56 * MB);
  float*          x1     = (float*)(ws + 64 * MB);
  unsigned short* mid    = (unsigned short*)(ws + 80 * MB);

  PrepArgs pa;
  pa.src[0] = wq; pa.dst[0] = wqkv_b;
  pa.src[1] = wk; pa.dst[1] = wqkv_b + (size_t)D_ * D_;
  pa.src[2] = wv; pa.dst[2] = wqkv_b + (size_t)2 * D_ * D_;
  pa.src[3] = wo; pa.dst[3] = wo_b;
  pa.src[4] = w1; pa.dst[4] = w1_b;
  pa.src[5] = w2; pa.dst[5] = w2_b;
  int q4 = D_ * D_ / 4, f4 = F_ * D_ / 4;
  pa.start[0] = 0;
  pa.start[1] = q4;
  pa.start[2] = 2 * q4;
  pa.start[3] = 3 * q4;
  pa.start[4] = 4 * q4;
  pa.start[5] = 4 * q4 + f4;
  pa.start[6] = 4 * q4 + 2 * f4;
  pa.x = x; pa.g1 = g1; pa.h = h_b;
  // fused prep: blocks 0..NTOK-1 = rmsnorm1, rest = weight cvt
  int cvt_blocks = (pa.start[6] + 255) / 256;
  prep_kernel<<<NTOK + cvt_blocks, 256, 0, stream>>>(pa);

  // fused QKV: N=3072, paired-K 128^2 / 256 thr, grid 24x32 (768 blocks)
  qkv_gemm<<<dim3(3 * D_ / 128, NTOK / 128), dim3(256), 0, stream>>>(
      h_b, wqkv_b, NTOK, 3 * D_, D_, q_b, k_b, vt_b);

  attn_kernel<<<dim3(512), dim3(256), 0, stream>>>(q_b, k_b, vt_b, o_b);

  // WO + residual: N=1024, 128^2 / 512 thr 4-deep, grid 8x32
  wo_gemm<<<dim3(D_ / 128, NTOK / 128), dim3(512), 0, stream>>>(
      o_b, wo_b, NTOK, D_, D_, x, x1);

  rmsnorm_kernel<<<NTOK, 256, 0, stream>>>(x1, g2, h_b);

  // FFN1 + fast GELU: N=4096, 256^2 BK=64 8-phase, grid 16x16 (256 blocks)
  ffn1_gemm<<<dim3(F_ / 256, NTOK / 256), dim3(512), 0, stream>>>(
      h_b, w1_b, NTOK, F_, D_, mid);

  // FFN2 + residual: N=1024, 128^2 / 512 thr 4-deep, grid 8x32
  ffn2_gemm<<<dim3(D_ / 128, NTOK / 128), dim3(512), 0, stream>>>(
      mid, w2_b, NTOK, D_, F_, x1, out);
}